// Round 11
// baseline (1095.371 us; speedup 1.0000x reference)
//
#include <hip/hip_runtime.h>

#define TT 96
#define FF 32
#define HH 128
#define G4 512
#define LOG2E 1.4426950408889634f

typedef _Float16 h2 __attribute__((ext_vector_type(2)));

__device__ __forceinline__ float fexp2(float x){ return __builtin_amdgcn_exp2f(x); }
__device__ __forceinline__ float frcp(float x){ return __builtin_amdgcn_rcpf(x); }
__device__ __forceinline__ float fsigmoid(float x){ return frcp(1.0f + fexp2(-LOG2E*x)); }
__device__ __forceinline__ float ftanh(float x){
    float u = fexp2(2.0f*LOG2E*x);
    return 1.0f - 2.0f*frcp(1.0f + u);
}
__device__ __forceinline__ h2 pk(float a, float b){
    h2 r; r.x = (_Float16)a; r.y = (_Float16)b; return r;
}
__device__ __forceinline__ unsigned pku(float a, float b){
    return __builtin_bit_cast(unsigned, pk(a, b));
}
__device__ __forceinline__ h2 u2h(unsigned v){ return __builtin_bit_cast(h2, v); }
__device__ __forceinline__ float fdot2(h2 a, h2 b, float c){
#if __has_builtin(__builtin_amdgcn_fdot2)
    return __builtin_amdgcn_fdot2(a, b, c, false);
#else
    return c + (float)a.x*(float)b.x + (float)a.y*(float)b.y;
#endif
}

// ---------------------------------------------------------------------------
// k_prep: G = fc_w[0:128]@dec_k packed f16 pairs, [g][u] uint4 layout.
// gy = fc_w[128]@dec_k; gb = fc_b@dec_k + dec_b.
// ---------------------------------------------------------------------------
__global__ __launch_bounds__(256) void k_prep(const float* __restrict__ fc_w,
                                              const float* __restrict__ fc_b,
                                              const float* __restrict__ dec_k,
                                              const float* __restrict__ dec_b,
                                              h2* __restrict__ Gp,
                                              float* __restrict__ gy,
                                              float* __restrict__ gb){
    int blk = blockIdx.x, tid = threadIdx.x;
    int u0 = tid, u1 = tid + 256;
    if (blk < 16){
        float a0[8], a1[8];
        #pragma unroll
        for (int r = 0; r < 8; ++r){ a0[r] = 0.f; a1[r] = 0.f; }
        for (int m = 0; m < 128; ++m){
            float d0 = dec_k[m*G4 + u0], d1 = dec_k[m*G4 + u1];
            #pragma unroll
            for (int r = 0; r < 8; ++r){
                float w = fc_w[(blk*8 + r)*HH + m];
                a0[r] += w * d0; a1[r] += w * d1;
            }
        }
        #pragma unroll
        for (int c = 0; c < 4; ++c){
            Gp[(blk*G4 + u0)*4 + c] = pk(a0[2*c], a0[2*c+1]);
            Gp[(blk*G4 + u1)*4 + c] = pk(a1[2*c], a1[2*c+1]);
        }
    } else if (blk == 16){
        float a0 = 0.f, a1 = 0.f;
        for (int m = 0; m < 128; ++m){
            float w = fc_w[128*HH + m];
            a0 += w * dec_k[m*G4 + u0]; a1 += w * dec_k[m*G4 + u1];
        }
        gy[u0] = a0; gy[u1] = a1;
    } else {
        float a0 = 0.f, a1 = 0.f;
        for (int m = 0; m < 128; ++m){
            float w = fc_b[m];
            a0 += w * dec_k[m*G4 + u0]; a1 += w * dec_k[m*G4 + u1];
        }
        gb[u0] = a0 + dec_b[u0]; gb[u1] = a1 + dec_b[u1];
    }
}

// ---------------------------------------------------------------------------
// k_enc: round-10 verbatim (known-good). Weights in LDS, rp_e[32] regs only.
// ---------------------------------------------------------------------------
__global__ __launch_bounds__(1024, 1) void k_enc(const float* __restrict__ inputs,
                                                 const float* __restrict__ enc_k,
                                                 const float* __restrict__ enc_r,
                                                 const float* __restrict__ enc_b,
                                                 const float* __restrict__ ae_w1,
                                                 const float* __restrict__ ae_b1,
                                                 const float* __restrict__ ae_w2,
                                                 float* __restrict__ ws_xenc){
    extern __shared__ float lds[];
    uint4* KLH4 = (uint4*)lds;            // [4][512] uint4 = 8192 floats
    float* XPJT = lds + 8192;             // [128][33] = 4224
    float* XIN  = lds + 12416;            // [96][32]  = 3072
    float* HST  = lds + 15488;            // 256 (h, s fp32 state)
    float* PP   = lds + 15744;            // 1024 partials
    float* PPZ  = lds + 16768;            // 1024 z-halves
    float* PE   = lds + 17792;            // 128
    float* W2E  = lds + 17920;            // 128
    float* AB1E = lds + 18048;            // 128
    h2*    HSP  = (h2*)(lds + 18176);     // 128 h2
    h2*    XTP  = (h2*)(lds + 18240);     // 16 h2
    uint4* WAE4 = (uint4*)(lds + 18256);  // [32][128] uint4 = 16384 floats
    // total 34640 floats = 138560 B

    const int b = blockIdx.x, tid = threadIdx.x;
    const int u = tid & 511, hf = tid >> 9;
    const int j7 = tid & 127, g8 = tid >> 7;
    const float* xin_g = inputs + b*TT*FF;

    for (int i = tid; i < TT*FF; i += 1024) XIN[i] = xin_g[i];
    for (int i = tid; i < 2048; i += 1024){
        int f8 = i >> 9, uu = i & 511;
        uint4 q;
        q.x = pku(enc_k[(f8*8+0)*G4+uu], enc_k[(f8*8+1)*G4+uu]);
        q.y = pku(enc_k[(f8*8+2)*G4+uu], enc_k[(f8*8+3)*G4+uu]);
        q.z = pku(enc_k[(f8*8+4)*G4+uu], enc_k[(f8*8+5)*G4+uu]);
        q.w = pku(enc_k[(f8*8+6)*G4+uu], enc_k[(f8*8+7)*G4+uu]);
        KLH4[i] = q;
    }
    for (int i = tid; i < 4096; i += 1024){
        int j = i & 127, i4g = i >> 7;
        int kbase = (i4g >> 2)*32 + (i4g & 3)*8;
        uint4 wv;
        wv.x = pku(ae_w1[(kbase+0)*HH + j], ae_w1[(kbase+1)*HH + j]);
        wv.y = pku(ae_w1[(kbase+2)*HH + j], ae_w1[(kbase+3)*HH + j]);
        wv.z = pku(ae_w1[(kbase+4)*HH + j], ae_w1[(kbase+5)*HH + j]);
        wv.w = pku(ae_w1[(kbase+6)*HH + j], ae_w1[(kbase+7)*HH + j]);
        WAE4[i] = wv;
    }
    if (tid < 128){ W2E[tid] = ae_w2[tid]; AB1E[tid] = ae_b1[tid]; HSP[tid] = pk(0.f, 0.f); }
    if (tid < 256) HST[tid] = 0.f;

    h2 rp_e[32];
    #pragma unroll
    for (int i = 0; i < 32; ++i)
        rp_e[i] = pk(enc_r[(hf*64 + 2*i)*G4 + u], enc_r[(hf*64 + 2*i+1)*G4 + u]);
    const float eb = (hf == 0) ? enc_b[u] : 0.f;
    __syncthreads();

    {   // XPJT[j][f] = sum_t x[t][f]*ae_w1[(256+t)*128+j]
        int j = tid & 127, fh = tid >> 7;
        float a0=0.f, a1=0.f, a2=0.f, a3=0.f;
        for (int t = 0; t < TT; ++t){
            float w = ae_w1[(256 + t)*HH + j];
            const float* xr = &XIN[t*FF + fh*4];
            a0 += xr[0]*w; a1 += xr[1]*w; a2 += xr[2]*w; a3 += xr[3]*w;
        }
        XPJT[j*33 + fh*4 + 0] = a0;
        XPJT[j*33 + fh*4 + 1] = a1;
        XPJT[j*33 + fh*4 + 2] = a2;
        XPJT[j*33 + fh*4 + 3] = a3;
    }
    __syncthreads();

    const uint4* HSP4 = (const uint4*)HSP;
    const uint4* XTP4 = (const uint4*)XTP;

    for (int t = 0; t < TT; ++t){
        {
            float a0 = 0.f, a1 = 0.f;
            #pragma unroll
            for (int i4 = 0; i4 < 4; ++i4){
                uint4 q  = HSP4[g8*4 + i4];
                uint4 wv = WAE4[(g8*4 + i4)*128 + j7];
                a0 = fdot2(u2h(q.x), u2h(wv.x), a0);
                a1 = fdot2(u2h(q.y), u2h(wv.y), a1);
                a0 = fdot2(u2h(q.z), u2h(wv.z), a0);
                a1 = fdot2(u2h(q.w), u2h(wv.w), a1);
            }
            PP[tid] = a0 + a1;
        }
        float z = eb;
        {
            float z2 = 0.f;
            #pragma unroll
            for (int i4 = 0; i4 < 8; ++i4){
                uint4 q = HSP4[hf*8 + i4];
                z  = fdot2(u2h(q.x), rp_e[i4*4+0], z);
                z2 = fdot2(u2h(q.y), rp_e[i4*4+1], z2);
                z  = fdot2(u2h(q.z), rp_e[i4*4+2], z);
                z2 = fdot2(u2h(q.w), rp_e[i4*4+3], z2);
            }
            z += z2;
        }
        __syncthreads();
        if (tid < 128){
            float s = AB1E[tid];
            #pragma unroll
            for (int g = 0; g < 8; ++g) s += PP[tid + 128*g];
            PE[tid] = s;
        }
        __syncthreads();
        {
            int f = tid & 31, jg = tid >> 5;
            float acc = 0.f;
            #pragma unroll
            for (int i = 0; i < 4; ++i){
                int j = jg*4 + i;
                acc += ftanh(PE[j] + XPJT[j*33 + f]) * W2E[j];
            }
            PP[tid] = acc;
        }
        __syncthreads();
        if (tid < 32){
            float e = 0.f;
            #pragma unroll
            for (int g = 0; g < 32; ++g) e += PP[g*32 + tid];
            float p = fexp2(e * LOG2E);
            float ss = p;
            #pragma unroll
            for (int d = 16; d; d >>= 1) ss += __shfl_xor(ss, d, 32);
            float xt = p * frcp(ss) * XIN[t*FF + tid];
            float xt2 = __shfl_xor(xt, 1);
            if (!(tid & 1)) XTP[tid >> 1] = pk(xt, xt2);
        }
        __syncthreads();
        {
            float z2 = 0.f;
            #pragma unroll
            for (int c = 0; c < 2; ++c){
                int f8 = hf*2 + c;
                uint4 kq = KLH4[f8*512 + u];
                uint4 xq = XTP4[f8];
                z  = fdot2(u2h(kq.x), u2h(xq.x), z);
                z2 = fdot2(u2h(kq.y), u2h(xq.y), z2);
                z  = fdot2(u2h(kq.z), u2h(xq.z), z);
                z2 = fdot2(u2h(kq.w), u2h(xq.w), z2);
            }
            PPZ[hf*512 + u] = z + z2;
        }
        __syncthreads();
        if (tid < 128){
            int j = tid;
            float zi = PPZ[j]       + PPZ[512 + j];
            float zf = PPZ[128 + j] + PPZ[640 + j];
            float zg = PPZ[256 + j] + PPZ[768 + j];
            float zo = PPZ[384 + j] + PPZ[896 + j];
            float iv = fsigmoid(zi);
            float fv = fsigmoid(zf);
            float gv = ftanh(zg);
            float ov = fsigmoid(zo);
            float cn = fv * HST[128 + j] + iv * gv;
            float hn = ov * ftanh(cn);
            HST[128 + j] = cn;
            HST[j] = hn;
            ws_xenc[(b*TT + t)*HH + j] = hn;
            float hn2 = __shfl_xor(hn, 1);
            float cn2 = __shfl_xor(cn, 1);
            if (!(j & 1)){
                HSP[j >> 1]        = pk(hn, hn2);
                HSP[64 + (j >> 1)] = pk(cn, cn2);
            }
        }
        __syncthreads();
    }
}

// ---------------------------------------------------------------------------
// k_xept: xeptT[b][j][t] = sum_k x_enc[b][t][k] * ad_w1[(256+k)*128 + j]
// ---------------------------------------------------------------------------
__global__ __launch_bounds__(256) void k_xept(const float* __restrict__ ws_xenc,
                                              const float* __restrict__ ad_w1,
                                              float* __restrict__ ws_xept){
    int b = blockIdx.x, q = blockIdx.y, tid = threadIdx.x;
    int j = tid & 127, th = tid >> 7;
    const float* xb = ws_xenc + b*TT*HH;
    float acc[12];
    #pragma unroll
    for (int i = 0; i < 12; ++i) acc[i] = 0.f;
    for (int k = 0; k < 128; ++k){
        float w = ad_w1[(256 + k)*HH + j];
        #pragma unroll
        for (int i = 0; i < 12; ++i){
            int tp = q*24 + th*12 + i;
            acc[i] += xb[tp*HH + k] * w;
        }
    }
    #pragma unroll
    for (int i = 0; i < 12; ++i){
        int tp = q*24 + th*12 + i;
        ws_xept[(b*HH + j)*TT + tp] = acc[i];
    }
}

// ---------------------------------------------------------------------------
// k_dec: round-10 base, 6 barriers/step (was 8). Round-11:
//  P1: shuffle att-proj with LDS weights WDCT[j*33 + m] (f16, padded) ->
//      APJ written directly (no reduce barrier). rp[32] is the ONLY reg array.
//  P2: EP=exp(e) + WS wave sums (softmax phase eliminated); ctx rebuilds
//      beta from EP broadcasts, 1/sum folded into ctx reduce.
// z-path (coalesced G, PPZ, gates) unchanged from round 10.
// ---------------------------------------------------------------------------
__global__ __launch_bounds__(1024, 1) void k_dec(const float* __restrict__ inputs,
                                                 const float* __restrict__ dec_r,
                                                 const float* __restrict__ ad_w1,
                                                 const float* __restrict__ ad_b1,
                                                 const float* __restrict__ ad_w2,
                                                 const float* __restrict__ ff_w,
                                                 const float* __restrict__ ff_b,
                                                 const h2* __restrict__ Gp,
                                                 const float* __restrict__ gy,
                                                 const float* __restrict__ gb,
                                                 const float* __restrict__ ws_xenc,
                                                 const float* __restrict__ ws_xept,
                                                 float* __restrict__ out){
    extern __shared__ float lds[];
    uint4* XE4 = (uint4*)lds;             // [12][128] uint4 = 6144 floats
    float* XPT = lds + 6144;              // [128][100] = 12800 (pad: bank spread)
    float* PP  = lds + 18944;             // 1024
    float* PPZ = lds + 19968;             // 1024
    float* DST = lds + 20992;             // 256: d, c
    float* APJ = lds + 21248;             // 128
    float* CTX = lds + 21376;             // 128
    float* W2L = lds + 21504;             // 128
    h2*    DCP = (h2*)(lds + 21632);      // 64 floats (128 h2)
    h2*    CXP = (h2*)(lds + 21696);      // 32 floats (64 h2)
    float* EP  = lds + 21728;             // 128 (96 used): exp(e)
    float* WS  = lds + 21856;             // 16 wave exp-partials
    float* YV  = lds + 21872;             // 96
    uint4* WDCT= (uint4*)(lds + 21968);   // [128][33] uint4 = 16896 floats
    // total 38864 floats = 155456 B

    const int b = blockIdx.x, tid = threadIdx.x;
    const int u = tid & 511, hf = tid >> 9;        // z mapping (coalesced)
    const int jA = tid >> 3, qA = tid & 7;         // attention shuffle mapping

    {   // x_enc -> LDS f16 t-pairs
        const float* xe_g = ws_xenc + b*TT*HH;
        for (int i = tid; i < 12*HH; i += 1024){
            int t8 = i >> 7, k = i & 127;
            uint4 qq;
            qq.x = pku(xe_g[(t8*8 + 0)*HH + k], xe_g[(t8*8 + 1)*HH + k]);
            qq.y = pku(xe_g[(t8*8 + 2)*HH + k], xe_g[(t8*8 + 3)*HH + k]);
            qq.z = pku(xe_g[(t8*8 + 4)*HH + k], xe_g[(t8*8 + 5)*HH + k]);
            qq.w = pku(xe_g[(t8*8 + 6)*HH + k], xe_g[(t8*8 + 7)*HH + k]);
            XE4[i] = qq;
        }
    }
    {   // xept -> LDS, stride 96 -> 100
        const float* src = ws_xept + b*HH*TT + jA*96 + qA*12;
        float* dst = &XPT[jA*100 + qA*12];
        #pragma unroll
        for (int i = 0; i < 12; ++i) dst[i] = src[i];
    }
    // ad_w1 rows 0..255 -> WDCT[j*33 + m]: f16 pairs of rows 8m..8m+7, col j
    for (int i = tid; i < 4096; i += 1024){
        int j = i >> 5, m = i & 31;
        uint4 wv;
        wv.x = pku(ad_w1[(8*m+0)*HH + j], ad_w1[(8*m+1)*HH + j]);
        wv.y = pku(ad_w1[(8*m+2)*HH + j], ad_w1[(8*m+3)*HH + j]);
        wv.z = pku(ad_w1[(8*m+4)*HH + j], ad_w1[(8*m+5)*HH + j]);
        wv.w = pku(ad_w1[(8*m+6)*HH + j], ad_w1[(8*m+7)*HH + j]);
        WDCT[j*33 + m] = wv;
    }
    if (tid < TT) YV[tid] = inputs[b*TT*FF + tid*FF + (FF-1)];
    if (tid < 128){ W2L[tid] = ad_w2[tid]; DCP[tid] = pk(0.f, 0.f); }
    if (tid < 256) DST[tid] = 0.f;

    h2 rp[32];
    #pragma unroll
    for (int i = 0; i < 32; ++i)
        rp[i] = pk(dec_r[(hf*64 + 2*i)*G4 + u], dec_r[(hf*64 + 2*i+1)*G4 + u]);
    const float gbr = gb[u], gyr = gy[u];
    const float ab1r = ad_b1[jA];

    __syncthreads();

    const uint4* GQ   = (const uint4*)Gp;
    const uint4* DCP4 = (const uint4*)DCP;
    const uint4* CXP4 = (const uint4*)CXP;

    for (int t = 0; t < TT; ++t){
        // P1: z-partial d@dec_r (u map, wave-uniform DCP broadcasts) +
        //     att-proj partial (qA map, WDCT from LDS) -> shuffle -> APJ
        float z = (hf == 0) ? (gbr + YV[t]*gyr) : 0.f;
        {
            float z2 = 0.f;
            #pragma unroll
            for (int i4 = 0; i4 < 8; ++i4){
                uint4 dq = DCP4[hf*8 + i4];
                z  = fdot2(u2h(dq.x), rp[i4*4+0], z);
                z2 = fdot2(u2h(dq.y), rp[i4*4+1], z2);
                z  = fdot2(u2h(dq.z), rp[i4*4+2], z);
                z2 = fdot2(u2h(dq.w), rp[i4*4+3], z2);
            }
            z += z2;
            float a0 = 0.f, a1 = 0.f;
            #pragma unroll
            for (int i4 = 0; i4 < 4; ++i4){
                uint4 dq = DCP4[qA*4 + i4];
                uint4 wv = WDCT[jA*33 + qA*4 + i4];
                a0 = fdot2(u2h(dq.x), u2h(wv.x), a0);
                a1 = fdot2(u2h(dq.y), u2h(wv.y), a1);
                a0 = fdot2(u2h(dq.z), u2h(wv.z), a0);
                a1 = fdot2(u2h(dq.w), u2h(wv.w), a1);
            }
            float aa = a0 + a1;
            aa += __shfl_xor(aa, 1);
            aa += __shfl_xor(aa, 2);
            aa += __shfl_xor(aa, 4);
            if (qA == 0) APJ[jA] = aa + ab1r;
        }
        __syncthreads();  // B1
        // P2: e[t'] via 8-lane shuffle -> EP=exp(e), WS wave sums
        {
            int tp = jA;
            float acc = 0.f;
            if (tp < TT){
                #pragma unroll
                for (int jj = 0; jj < 16; ++jj){
                    int jx = qA + 8*jj;
                    acc += ftanh(APJ[jx] + XPT[jx*100 + tp]) * W2L[jx];
                }
            }
            acc += __shfl_xor(acc, 1);
            acc += __shfl_xor(acc, 2);
            acc += __shfl_xor(acc, 4);
            float p = 0.f;
            if (qA == 0 && tp < TT){ p = fexp2(acc * LOG2E); EP[tp] = p; }
            float pw = p;
            pw += __shfl_xor(pw, 8);
            pw += __shfl_xor(pw, 16);
            pw += __shfl_xor(pw, 32);
            if ((tid & 63) == 0) WS[tid >> 6] = pw;
        }
        __syncthreads();  // B2
        // P3: ctx partials, beta rebuilt from EP broadcasts (wave-uniform t8)
        {
            int k = tid & 127, th = tid >> 7;
            int t8a = (th < 4) ? th*2 : th + 4;
            int cnt = (th < 4) ? 2 : 1;
            float a = 0.f;
            for (int i = 0; i < cnt; ++i){
                int t8 = t8a + i;
                float4 e0 = *(const float4*)&EP[t8*8];
                float4 e1 = *(const float4*)&EP[t8*8 + 4];
                h2 b0 = pk(e0.x, e0.y), b1 = pk(e0.z, e0.w);
                h2 b2 = pk(e1.x, e1.y), b3 = pk(e1.z, e1.w);
                uint4 xq = XE4[t8*HH + k];
                a = fdot2(u2h(xq.x), b0, a);
                a = fdot2(u2h(xq.y), b1, a);
                a = fdot2(u2h(xq.z), b2, a);
                a = fdot2(u2h(xq.w), b3, a);
            }
            PP[tid] = a;
        }
        __syncthreads();  // B3
        // P4: ctx reduce + normalize (1/sum from WS, redundant per lane)
        if (tid < 128){
            float4 w0 = *(const float4*)&WS[0];
            float4 w1 = *(const float4*)&WS[4];
            float4 w2 = *(const float4*)&WS[8];
            float4 w3 = *(const float4*)&WS[12];
            float ssum = (w0.x+w0.y+w0.z+w0.w) + (w1.x+w1.y+w1.z+w1.w)
                       + (w2.x+w2.y+w2.z+w2.w) + (w3.x+w3.y+w3.z+w3.w);
            float inv = frcp(ssum);
            float s = 0.f;
            #pragma unroll
            for (int g = 0; g < 8; ++g) s += PP[tid + 128*g];
            float cv = s * inv;
            CTX[tid] = cv;
            float cv2 = __shfl_xor(cv, 1);
            if (!(tid & 1)) CXP[tid >> 1] = pk(cv, cv2);
        }
        __syncthreads();  // B4
        // P5: z += ctx@G (coalesced G from L2, wave-uniform CXP) -> PPZ
        {
            float z2 = 0.f;
            #pragma unroll
            for (int gi = 0; gi < 8; ++gi){
                int g = hf*8 + gi;
                uint4 gq = GQ[g*G4 + u];
                uint4 cc = CXP4[g];
                z  = fdot2(u2h(gq.x), u2h(cc.x), z);
                z2 = fdot2(u2h(gq.y), u2h(cc.y), z2);
                z  = fdot2(u2h(gq.z), u2h(cc.z), z);
                z2 = fdot2(u2h(gq.w), u2h(cc.w), z2);
            }
            PPZ[hf*512 + u] = z + z2;
        }
        __syncthreads();  // B5
        // P6: gates (combine z-halves) + state update
        if (tid < 128){
            int j = tid;
            float zi = PPZ[j]       + PPZ[512 + j];
            float zf = PPZ[128 + j] + PPZ[640 + j];
            float zg = PPZ[256 + j] + PPZ[768 + j];
            float zo = PPZ[384 + j] + PPZ[896 + j];
            float iv = fsigmoid(zi);
            float fv = fsigmoid(zf);
            float gv = ftanh(zg);
            float ov = fsigmoid(zo);
            float cn = fv * DST[128 + j] + iv * gv;
            float hn = ov * ftanh(cn);
            DST[128 + j] = cn;
            DST[j] = hn;
            float hn2 = __shfl_xor(hn, 1);
            float cn2 = __shfl_xor(cn, 1);
            if (!(j & 1)){
                DCP[j >> 1]        = pk(hn, hn2);
                DCP[64 + (j >> 1)] = pk(cn, cn2);
            }
        }
        __syncthreads();  // B6
    }

    // output: y_pred = [d_n, ctx] @ ff_w + ff_b (fp32)
    {
        int jp = tid & 31, sg = tid >> 5;
        float a = 0.f;
        #pragma unroll
        for (int kk = 0; kk < 8; ++kk){
            int k = sg*8 + kk;
            float val = (k < 128) ? DST[k] : CTX[k - 128];
            a += val * ff_w[k*FF + jp];
        }
        PP[sg*32 + jp] = a;
    }
    __syncthreads();
    if (tid < 32){
        float o = ff_b[tid];
        #pragma unroll
        for (int s = 0; s < 32; ++s) o += PP[s*32 + tid];
        out[b*FF + tid] = o;
    }
}

// ---------------------------------------------------------------------------
extern "C" void kernel_launch(void* const* d_in, const int* in_sizes, int n_in,
                              void* d_out, int out_size, void* d_ws, size_t ws_size,
                              hipStream_t stream) {
    const float* inputs = (const float*)d_in[0];
    const float* enc_k  = (const float*)d_in[1];
    const float* enc_r  = (const float*)d_in[2];
    const float* enc_b  = (const float*)d_in[3];
    const float* ae_w1  = (const float*)d_in[4];
    const float* ae_b1  = (const float*)d_in[5];
    const float* ae_w2  = (const float*)d_in[6];
    // d_in[7] = ae_b2 (softmax-invariant, unused)
    const float* dec_k  = (const float*)d_in[8];
    const float* dec_r  = (const float*)d_in[9];
    const float* dec_b  = (const float*)d_in[10];
    const float* ad_w1  = (const float*)d_in[11];
    const float* ad_b1  = (const float*)d_in[12];
    const float* ad_w2  = (const float*)d_in[13];
    // d_in[14] = ad_b2 (softmax-invariant, unused)
    const float* fc_w   = (const float*)d_in[15];
    const float* fc_b   = (const float*)d_in[16];
    const float* ff_w   = (const float*)d_in[17];
    const float* ff_b   = (const float*)d_in[18];

    float* ws      = (float*)d_ws;
    float* ws_xenc = ws;                     // 64*96*128 floats
    float* ws_xept = ws + 786432;            // 64*128*96 floats
    h2*    Gp      = (h2*)(ws + 1572864);    // 32768 h2 (128 KB)
    float* gy      = ws + 1605632;           // 512
    float* gb      = ws + 1606144;           // 512

    hipFuncSetAttribute((const void*)k_enc, hipFuncAttributeMaxDynamicSharedMemorySize, 138560);
    hipFuncSetAttribute((const void*)k_dec, hipFuncAttributeMaxDynamicSharedMemorySize, 155456);

    k_prep<<<18, 256, 0, stream>>>(fc_w, fc_b, dec_k, dec_b, Gp, gy, gb);
    k_enc<<<64, 1024, 138560, stream>>>(inputs, enc_k, enc_r, enc_b, ae_w1, ae_b1, ae_w2, ws_xenc);
    k_xept<<<dim3(64, 4), 256, 0, stream>>>(ws_xenc, ad_w1, ws_xept);
    k_dec<<<64, 1024, 155456, stream>>>(inputs, dec_r, ad_w1, ad_b1, ad_w2, ff_w, ff_b,
                                        Gp, gy, gb, ws_xenc, ws_xept, (float*)d_out);
}

// Round 12
// 966.763 us; speedup vs baseline: 1.1330x; 1.1330x over previous
//
#include <hip/hip_runtime.h>

#define TT 96
#define FF 32
#define HH 128
#define G4 512
#define LOG2E 1.4426950408889634f

typedef _Float16 h2 __attribute__((ext_vector_type(2)));

__device__ __forceinline__ float fexp2(float x){ return __builtin_amdgcn_exp2f(x); }
__device__ __forceinline__ float frcp(float x){ return __builtin_amdgcn_rcpf(x); }
__device__ __forceinline__ float fsigmoid(float x){ return frcp(1.0f + fexp2(-LOG2E*x)); }
__device__ __forceinline__ float ftanh(float x){
    float u = fexp2(2.0f*LOG2E*x);
    return 1.0f - 2.0f*frcp(1.0f + u);
}
__device__ __forceinline__ h2 pk(float a, float b){
    h2 r; r.x = (_Float16)a; r.y = (_Float16)b; return r;
}
__device__ __forceinline__ unsigned pku(float a, float b){
    return __builtin_bit_cast(unsigned, pk(a, b));
}
__device__ __forceinline__ h2 u2h(unsigned v){ return __builtin_bit_cast(h2, v); }
__device__ __forceinline__ float fdot2(h2 a, h2 b, float c){
#if __has_builtin(__builtin_amdgcn_fdot2)
    return __builtin_amdgcn_fdot2(a, b, c, false);
#else
    return c + (float)a.x*(float)b.x + (float)a.y*(float)b.y;
#endif
}

// ---------------------------------------------------------------------------
// k_prep: G = fc_w[0:128]@dec_k packed f16 pairs, [g][u] uint4 layout.
// gy = fc_w[128]@dec_k; gb = fc_b@dec_k + dec_b.
// ---------------------------------------------------------------------------
__global__ __launch_bounds__(256) void k_prep(const float* __restrict__ fc_w,
                                              const float* __restrict__ fc_b,
                                              const float* __restrict__ dec_k,
                                              const float* __restrict__ dec_b,
                                              h2* __restrict__ Gp,
                                              float* __restrict__ gy,
                                              float* __restrict__ gb){
    int blk = blockIdx.x, tid = threadIdx.x;
    int u0 = tid, u1 = tid + 256;
    if (blk < 16){
        float a0[8], a1[8];
        #pragma unroll
        for (int r = 0; r < 8; ++r){ a0[r] = 0.f; a1[r] = 0.f; }
        for (int m = 0; m < 128; ++m){
            float d0 = dec_k[m*G4 + u0], d1 = dec_k[m*G4 + u1];
            #pragma unroll
            for (int r = 0; r < 8; ++r){
                float w = fc_w[(blk*8 + r)*HH + m];
                a0[r] += w * d0; a1[r] += w * d1;
            }
        }
        #pragma unroll
        for (int c = 0; c < 4; ++c){
            Gp[(blk*G4 + u0)*4 + c] = pk(a0[2*c], a0[2*c+1]);
            Gp[(blk*G4 + u1)*4 + c] = pk(a1[2*c], a1[2*c+1]);
        }
    } else if (blk == 16){
        float a0 = 0.f, a1 = 0.f;
        for (int m = 0; m < 128; ++m){
            float w = fc_w[128*HH + m];
            a0 += w * dec_k[m*G4 + u0]; a1 += w * dec_k[m*G4 + u1];
        }
        gy[u0] = a0; gy[u1] = a1;
    } else {
        float a0 = 0.f, a1 = 0.f;
        for (int m = 0; m < 128; ++m){
            float w = fc_b[m];
            a0 += w * dec_k[m*G4 + u0]; a1 += w * dec_k[m*G4 + u1];
        }
        gb[u0] = a0 + dec_b[u0]; gb[u1] = a1 + dec_b[u1];
    }
}

// ---------------------------------------------------------------------------
// k_main: fused encoder + xept + decoder. One block per batch, 1024 threads.
// Stage A = round-10 k_enc verbatim (LDS layout A, aliased at base).
// Stage B = round-10 k_dec verbatim + in-kernel xept into XPT (stride 100).
// All LDS regions are re-staged after the stage barrier, so aliasing is safe.
// ---------------------------------------------------------------------------
__global__ __launch_bounds__(1024, 1) void k_main(const float* __restrict__ inputs,
                                                  const float* __restrict__ enc_k,
                                                  const float* __restrict__ enc_r,
                                                  const float* __restrict__ enc_b,
                                                  const float* __restrict__ ae_w1,
                                                  const float* __restrict__ ae_b1,
                                                  const float* __restrict__ ae_w2,
                                                  const float* __restrict__ dec_r,
                                                  const float* __restrict__ ad_w1,
                                                  const float* __restrict__ ad_b1,
                                                  const float* __restrict__ ad_w2,
                                                  const float* __restrict__ ff_w,
                                                  const float* __restrict__ ff_b,
                                                  const h2* __restrict__ Gp,
                                                  const float* __restrict__ gy,
                                                  const float* __restrict__ gb,
                                                  float* __restrict__ ws_xenc,
                                                  float* __restrict__ out){
    extern __shared__ float lds[];
    const int b = blockIdx.x, tid = threadIdx.x;

    // ======================= STAGE A: encoder =======================
    {
        uint4* KLH4 = (uint4*)lds;            // [4][512] uint4 = 8192 floats
        float* XPJT = lds + 8192;             // [128][33] = 4224
        float* XIN  = lds + 12416;            // [96][32]  = 3072
        float* HST  = lds + 15488;            // 256 (h, s fp32 state)
        float* PP   = lds + 15744;            // 1024 partials
        float* PPZ  = lds + 16768;            // 1024 z-halves
        float* PE   = lds + 17792;            // 128
        float* W2E  = lds + 17920;            // 128
        float* AB1E = lds + 18048;            // 128
        h2*    HSP  = (h2*)(lds + 18176);     // 128 h2
        h2*    XTP  = (h2*)(lds + 18240);     // 16 h2
        uint4* WAE4 = (uint4*)(lds + 18248);  // [32][128] uint4 = 16384 floats
        // stage-A total 34632 floats = 138528 B

        const int u = tid & 511, hf = tid >> 9;
        const int j7 = tid & 127, g8 = tid >> 7;
        const float* xin_g = inputs + b*TT*FF;

        for (int i = tid; i < TT*FF; i += 1024) XIN[i] = xin_g[i];
        for (int i = tid; i < 2048; i += 1024){
            int f8 = i >> 9, uu = i & 511;
            uint4 q;
            q.x = pku(enc_k[(f8*8+0)*G4+uu], enc_k[(f8*8+1)*G4+uu]);
            q.y = pku(enc_k[(f8*8+2)*G4+uu], enc_k[(f8*8+3)*G4+uu]);
            q.z = pku(enc_k[(f8*8+4)*G4+uu], enc_k[(f8*8+5)*G4+uu]);
            q.w = pku(enc_k[(f8*8+6)*G4+uu], enc_k[(f8*8+7)*G4+uu]);
            KLH4[i] = q;
        }
        for (int i = tid; i < 4096; i += 1024){
            int j = i & 127, i4g = i >> 7;
            int kbase = (i4g >> 2)*32 + (i4g & 3)*8;
            uint4 wv;
            wv.x = pku(ae_w1[(kbase+0)*HH + j], ae_w1[(kbase+1)*HH + j]);
            wv.y = pku(ae_w1[(kbase+2)*HH + j], ae_w1[(kbase+3)*HH + j]);
            wv.z = pku(ae_w1[(kbase+4)*HH + j], ae_w1[(kbase+5)*HH + j]);
            wv.w = pku(ae_w1[(kbase+6)*HH + j], ae_w1[(kbase+7)*HH + j]);
            WAE4[i] = wv;
        }
        if (tid < 128){ W2E[tid] = ae_w2[tid]; AB1E[tid] = ae_b1[tid]; HSP[tid] = pk(0.f, 0.f); }
        if (tid < 256) HST[tid] = 0.f;

        h2 rp_e[32];
        #pragma unroll
        for (int i = 0; i < 32; ++i)
            rp_e[i] = pk(enc_r[(hf*64 + 2*i)*G4 + u], enc_r[(hf*64 + 2*i+1)*G4 + u]);
        const float eb = (hf == 0) ? enc_b[u] : 0.f;
        __syncthreads();

        {   // XPJT[j][f] = sum_t x[t][f]*ae_w1[(256+t)*128+j]
            int j = tid & 127, fh = tid >> 7;
            float a0=0.f, a1=0.f, a2=0.f, a3=0.f;
            for (int t = 0; t < TT; ++t){
                float w = ae_w1[(256 + t)*HH + j];
                const float* xr = &XIN[t*FF + fh*4];
                a0 += xr[0]*w; a1 += xr[1]*w; a2 += xr[2]*w; a3 += xr[3]*w;
            }
            XPJT[j*33 + fh*4 + 0] = a0;
            XPJT[j*33 + fh*4 + 1] = a1;
            XPJT[j*33 + fh*4 + 2] = a2;
            XPJT[j*33 + fh*4 + 3] = a3;
        }
        __syncthreads();

        const uint4* HSP4 = (const uint4*)HSP;
        const uint4* XTP4 = (const uint4*)XTP;

        for (int t = 0; t < TT; ++t){
            {
                float a0 = 0.f, a1 = 0.f;
                #pragma unroll
                for (int i4 = 0; i4 < 4; ++i4){
                    uint4 q  = HSP4[g8*4 + i4];
                    uint4 wv = WAE4[(g8*4 + i4)*128 + j7];
                    a0 = fdot2(u2h(q.x), u2h(wv.x), a0);
                    a1 = fdot2(u2h(q.y), u2h(wv.y), a1);
                    a0 = fdot2(u2h(q.z), u2h(wv.z), a0);
                    a1 = fdot2(u2h(q.w), u2h(wv.w), a1);
                }
                PP[tid] = a0 + a1;
            }
            float z = eb;
            {
                float z2 = 0.f;
                #pragma unroll
                for (int i4 = 0; i4 < 8; ++i4){
                    uint4 q = HSP4[hf*8 + i4];
                    z  = fdot2(u2h(q.x), rp_e[i4*4+0], z);
                    z2 = fdot2(u2h(q.y), rp_e[i4*4+1], z2);
                    z  = fdot2(u2h(q.z), rp_e[i4*4+2], z);
                    z2 = fdot2(u2h(q.w), rp_e[i4*4+3], z2);
                }
                z += z2;
            }
            __syncthreads();
            if (tid < 128){
                float s = AB1E[tid];
                #pragma unroll
                for (int g = 0; g < 8; ++g) s += PP[tid + 128*g];
                PE[tid] = s;
            }
            __syncthreads();
            {
                int f = tid & 31, jg = tid >> 5;
                float acc = 0.f;
                #pragma unroll
                for (int i = 0; i < 4; ++i){
                    int j = jg*4 + i;
                    acc += ftanh(PE[j] + XPJT[j*33 + f]) * W2E[j];
                }
                PP[tid] = acc;
            }
            __syncthreads();
            if (tid < 32){
                float e = 0.f;
                #pragma unroll
                for (int g = 0; g < 32; ++g) e += PP[g*32 + tid];
                float p = fexp2(e * LOG2E);
                float ss = p;
                #pragma unroll
                for (int d = 16; d; d >>= 1) ss += __shfl_xor(ss, d, 32);
                float xt = p * frcp(ss) * XIN[t*FF + tid];
                float xt2 = __shfl_xor(xt, 1);
                if (!(tid & 1)) XTP[tid >> 1] = pk(xt, xt2);
            }
            __syncthreads();
            {
                float z2 = 0.f;
                #pragma unroll
                for (int c = 0; c < 2; ++c){
                    int f8 = hf*2 + c;
                    uint4 kq = KLH4[f8*512 + u];
                    uint4 xq = XTP4[f8];
                    z  = fdot2(u2h(kq.x), u2h(xq.x), z);
                    z2 = fdot2(u2h(kq.y), u2h(xq.y), z2);
                    z  = fdot2(u2h(kq.z), u2h(xq.z), z);
                    z2 = fdot2(u2h(kq.w), u2h(xq.w), z2);
                }
                PPZ[hf*512 + u] = z + z2;
            }
            __syncthreads();
            if (tid < 128){
                int j = tid;
                float zi = PPZ[j]       + PPZ[512 + j];
                float zf = PPZ[128 + j] + PPZ[640 + j];
                float zg = PPZ[256 + j] + PPZ[768 + j];
                float zo = PPZ[384 + j] + PPZ[896 + j];
                float iv = fsigmoid(zi);
                float fv = fsigmoid(zf);
                float gv = ftanh(zg);
                float ov = fsigmoid(zo);
                float cn = fv * HST[128 + j] + iv * gv;
                float hn = ov * ftanh(cn);
                HST[128 + j] = cn;
                HST[j] = hn;
                ws_xenc[(b*TT + t)*HH + j] = hn;
                float hn2 = __shfl_xor(hn, 1);
                float cn2 = __shfl_xor(cn, 1);
                if (!(j & 1)){
                    HSP[j >> 1]        = pk(hn, hn2);
                    HSP[64 + (j >> 1)] = pk(cn, cn2);
                }
            }
            __syncthreads();
        }
    }
    __syncthreads();

    // ======================= STAGE B: xept + decoder =======================
    {
        uint4* XE4 = (uint4*)lds;             // [12][128] uint4 = 6144 floats
        float* XPT = lds + 6144;              // [128][100] = 12800 (pad 100)
        float* PP  = lds + 18944;             // 1024
        float* PPZ = lds + 19968;             // 1024
        float* DST = lds + 20992;             // 256: d, c
        float* APJ = lds + 21248;             // 128
        float* CTX = lds + 21376;             // 128
        float* W2L = lds + 21504;             // 128
        float* SCAL= lds + 21632;             // 8
        h2*    DCP = (h2*)(lds + 21640);      // 64 floats (128 h2)
        h2*    CXP = (h2*)(lds + 21704);      // 32 floats (64 h2)
        h2*    BEP = (h2*)(lds + 21736);      // 32 floats (64 h2, 48 used)
        float* YV  = lds + 21768;             // 96
        uint4* WDC4= (uint4*)(lds + 21864);   // [32][128] uint4 = 16384 floats
        // stage-B total 38248 floats = 152992 B

        const int u = tid & 511, hf = tid >> 9;        // unit, k-half
        const int j7 = tid & 127, g8 = tid >> 7;       // attention mapping

        {   // in-kernel xept: XPT[j*100 + tp] = sum_k x_enc[tp][k]*ad_w1[(256+k)*HH+j]
            int j = tid & 127, th = tid >> 7;
            const float* xb = ws_xenc + b*TT*HH;
            float acc[12];
            #pragma unroll
            for (int i = 0; i < 12; ++i) acc[i] = 0.f;
            for (int k = 0; k < 128; ++k){
                float w = ad_w1[(256 + k)*HH + j];
                #pragma unroll
                for (int i = 0; i < 12; ++i)
                    acc[i] += xb[(th*12 + i)*HH + k] * w;   // wave-uniform -> scalar load
            }
            #pragma unroll
            for (int i = 0; i < 12; ++i)
                XPT[j*100 + th*12 + i] = acc[i];
        }
        {   // x_enc -> LDS f16 t-pairs
            const float* xe_g = ws_xenc + b*TT*HH;
            for (int i = tid; i < 12*HH; i += 1024){
                int t8 = i >> 7, k = i & 127;
                uint4 qq;
                qq.x = pku(xe_g[(t8*8 + 0)*HH + k], xe_g[(t8*8 + 1)*HH + k]);
                qq.y = pku(xe_g[(t8*8 + 2)*HH + k], xe_g[(t8*8 + 3)*HH + k]);
                qq.z = pku(xe_g[(t8*8 + 4)*HH + k], xe_g[(t8*8 + 5)*HH + k]);
                qq.w = pku(xe_g[(t8*8 + 6)*HH + k], xe_g[(t8*8 + 7)*HH + k]);
                XE4[i] = qq;
            }
        }
        // ad_w1 rows 0..255 -> f16 LDS
        for (int i = tid; i < 4096; i += 1024){
            int j = i & 127, i4g = i >> 7;
            int kbase = (i4g >> 2)*32 + (i4g & 3)*8;
            uint4 wv;
            wv.x = pku(ad_w1[(kbase+0)*HH + j], ad_w1[(kbase+1)*HH + j]);
            wv.y = pku(ad_w1[(kbase+2)*HH + j], ad_w1[(kbase+3)*HH + j]);
            wv.z = pku(ad_w1[(kbase+4)*HH + j], ad_w1[(kbase+5)*HH + j]);
            wv.w = pku(ad_w1[(kbase+6)*HH + j], ad_w1[(kbase+7)*HH + j]);
            WDC4[i] = wv;
        }
        if (tid < TT) YV[tid] = inputs[b*TT*FF + tid*FF + (FF-1)];
        if (tid < 128){ W2L[tid] = ad_w2[tid]; DCP[tid] = pk(0.f, 0.f); }
        if (tid < 256) DST[tid] = 0.f;

        h2 rp[32];
        #pragma unroll
        for (int i = 0; i < 32; ++i)
            rp[i] = pk(dec_r[(hf*64 + 2*i)*G4 + u], dec_r[(hf*64 + 2*i+1)*G4 + u]);
        const float gbr = gb[u], gyr = gy[u];
        const float ab1 = (tid < 128) ? ad_b1[tid] : 0.f;

        __syncthreads();

        const uint4* GQ   = (const uint4*)Gp;
        const uint4* DCP4 = (const uint4*)DCP;
        const uint4* CXP4 = (const uint4*)CXP;
        const uint4* BEP4 = (const uint4*)BEP;

        for (int t = 0; t < TT; ++t){
            // PH-1: att-proj partials, weights from LDS
            {
                float a0 = 0.f, a1 = 0.f;
                #pragma unroll
                for (int i4 = 0; i4 < 4; ++i4){
                    uint4 q  = DCP4[g8*4 + i4];
                    uint4 wv = WDC4[(g8*4 + i4)*128 + j7];
                    a0 = fdot2(u2h(q.x), u2h(wv.x), a0);
                    a1 = fdot2(u2h(q.y), u2h(wv.y), a1);
                    a0 = fdot2(u2h(q.z), u2h(wv.z), a0);
                    a1 = fdot2(u2h(q.w), u2h(wv.w), a1);
                }
                PP[tid] = a0 + a1;
            }
            // PH-5a: z-half from d@dec_r
            float z = (hf == 0) ? (gbr + YV[t]*gyr) : 0.f;
            {
                float z2 = 0.f;
                #pragma unroll
                for (int i4 = 0; i4 < 8; ++i4){
                    uint4 q = DCP4[hf*8 + i4];
                    z  = fdot2(u2h(q.x), rp[i4*4+0], z);
                    z2 = fdot2(u2h(q.y), rp[i4*4+1], z2);
                    z  = fdot2(u2h(q.z), rp[i4*4+2], z);
                    z2 = fdot2(u2h(q.w), rp[i4*4+3], z2);
                }
                z += z2;
            }
            __syncthreads();
            if (tid < 128){
                float s = ab1;
                #pragma unroll
                for (int g = 0; g < 8; ++g) s += PP[tid + 128*g];
                APJ[tid] = s;
            }
            __syncthreads();
            // PH-2: e[t'] partials (8 j-chunks of 16) — xept from LDS (stride 100)
            {
                int tp = tid & 127, jg = tid >> 7;
                float acc = 0.f;
                if (tp < TT){
                    const float* xrow = &XPT[(jg*16)*100 + tp];
                    #pragma unroll
                    for (int q4 = 0; q4 < 4; ++q4){
                        float4 aj = *(const float4*)&APJ[jg*16 + q4*4];
                        float4 wj = *(const float4*)&W2L[jg*16 + q4*4];
                        acc += ftanh(aj.x + xrow[(q4*4+0)*100]) * wj.x;
                        acc += ftanh(aj.y + xrow[(q4*4+1)*100]) * wj.y;
                        acc += ftanh(aj.z + xrow[(q4*4+2)*100]) * wj.z;
                        acc += ftanh(aj.w + xrow[(q4*4+3)*100]) * wj.w;
                    }
                }
                PP[tid] = acc;
            }
            __syncthreads();
            // softmax over 96 on wave 0 (no max-sub); packed beta pairs
            if (tid < 64){
                float ea = 0.f;
                #pragma unroll
                for (int g = 0; g < 8; ++g) ea += PP[tid + 128*g];
                float pa = fexp2(ea * LOG2E);
                float pb = 0.f;
                if (tid < 32){
                    float ebv = 0.f;
                    #pragma unroll
                    for (int g = 0; g < 8; ++g) ebv += PP[64 + tid + 128*g];
                    pb = fexp2(ebv * LOG2E);
                }
                float ss = pa + pb;
                #pragma unroll
                for (int d = 32; d; d >>= 1) ss += __shfl_xor(ss, d, 64);
                float pa2 = __shfl_xor(pa, 1);
                float pb2 = __shfl_xor(pb, 1);
                if (!(tid & 1)){
                    BEP[tid >> 1] = pk(pa, pa2);
                    if (tid < 32) BEP[32 + (tid >> 1)] = pk(pb, pb2);
                }
                if (tid == 0) SCAL[0] = frcp(ss);
            }
            __syncthreads();
            // PH-4: ctx partials
            {
                int k = tid & 127, th = tid >> 7;
                int t8a = (th < 4) ? th*2 : th + 4;
                int cnt = (th < 4) ? 2 : 1;
                float a = 0.f;
                for (int i = 0; i < cnt; ++i){
                    int t8 = t8a + i;
                    uint4 q  = XE4[t8*HH + k];
                    uint4 bb = BEP4[t8];
                    a = fdot2(u2h(q.x), u2h(bb.x), a);
                    a = fdot2(u2h(q.y), u2h(bb.y), a);
                    a = fdot2(u2h(q.z), u2h(bb.z), a);
                    a = fdot2(u2h(q.w), u2h(bb.w), a);
                }
                PP[tid] = a;
            }
            __syncthreads();
            if (tid < 128){
                float s = 0.f;
                #pragma unroll
                for (int g = 0; g < 8; ++g) s += PP[tid + 128*g];
                float cv = s * SCAL[0];
                CTX[tid] = cv;
                float cv2 = __shfl_xor(cv, 1);
                if (!(tid & 1)) CXP[tid >> 1] = pk(cv, cv2);
            }
            __syncthreads();
            // PH-5b: z-half += ctx@G (G streamed from L2)
            {
                float z2 = 0.f;
                #pragma unroll
                for (int gi = 0; gi < 8; ++gi){
                    int g = hf*8 + gi;
                    uint4 q  = GQ[g*G4 + u];
                    uint4 cc = CXP4[g];
                    z  = fdot2(u2h(q.x), u2h(cc.x), z);
                    z2 = fdot2(u2h(q.y), u2h(cc.y), z2);
                    z  = fdot2(u2h(q.z), u2h(cc.z), z);
                    z2 = fdot2(u2h(q.w), u2h(cc.w), z2);
                }
                PPZ[hf*512 + u] = z + z2;
            }
            __syncthreads();
            // PH-6: gates + state
            if (tid < 128){
                int j = tid;
                float zi = PPZ[j]       + PPZ[512 + j];
                float zf = PPZ[128 + j] + PPZ[640 + j];
                float zg = PPZ[256 + j] + PPZ[768 + j];
                float zo = PPZ[384 + j] + PPZ[896 + j];
                float iv = fsigmoid(zi);
                float fv = fsigmoid(zf);
                float gv = ftanh(zg);
                float ov = fsigmoid(zo);
                float cn = fv * DST[128 + j] + iv * gv;
                float hn = ov * ftanh(cn);
                DST[128 + j] = cn;
                DST[j] = hn;
                float hn2 = __shfl_xor(hn, 1);
                float cn2 = __shfl_xor(cn, 1);
                if (!(j & 1)){
                    DCP[j >> 1]        = pk(hn, hn2);
                    DCP[64 + (j >> 1)] = pk(cn, cn2);
                }
            }
            __syncthreads();
        }

        // output: y_pred = [d_n, ctx] @ ff_w + ff_b (fp32)
        {
            int jp = tid & 31, sg = tid >> 5;
            float a = 0.f;
            #pragma unroll
            for (int kk = 0; kk < 8; ++kk){
                int k = sg*8 + kk;
                float val = (k < 128) ? DST[k] : CTX[k - 128];
                a += val * ff_w[k*FF + jp];
            }
            PP[sg*32 + jp] = a;
        }
        __syncthreads();
        if (tid < 32){
            float o = ff_b[tid];
            #pragma unroll
            for (int s = 0; s < 32; ++s) o += PP[s*32 + tid];
            out[b*FF + tid] = o;
        }
    }
}

// ---------------------------------------------------------------------------
extern "C" void kernel_launch(void* const* d_in, const int* in_sizes, int n_in,
                              void* d_out, int out_size, void* d_ws, size_t ws_size,
                              hipStream_t stream) {
    const float* inputs = (const float*)d_in[0];
    const float* enc_k  = (const float*)d_in[1];
    const float* enc_r  = (const float*)d_in[2];
    const float* enc_b  = (const float*)d_in[3];
    const float* ae_w1  = (const float*)d_in[4];
    const float* ae_b1  = (const float*)d_in[5];
    const float* ae_w2  = (const float*)d_in[6];
    // d_in[7] = ae_b2 (softmax-invariant, unused)
    const float* dec_k  = (const float*)d_in[8];
    const float* dec_r  = (const float*)d_in[9];
    const float* dec_b  = (const float*)d_in[10];
    const float* ad_w1  = (const float*)d_in[11];
    const float* ad_b1  = (const float*)d_in[12];
    const float* ad_w2  = (const float*)d_in[13];
    // d_in[14] = ad_b2 (softmax-invariant, unused)
    const float* fc_w   = (const float*)d_in[15];
    const float* fc_b   = (const float*)d_in[16];
    const float* ff_w   = (const float*)d_in[17];
    const float* ff_b   = (const float*)d_in[18];

    float* ws      = (float*)d_ws;
    float* ws_xenc = ws;                     // 64*96*128 floats
    h2*    Gp      = (h2*)(ws + 1572864);    // 32768 h2 (128 KB)
    float* gy      = ws + 1605632;           // 512
    float* gb      = ws + 1606144;           // 512

    hipFuncSetAttribute((const void*)k_main, hipFuncAttributeMaxDynamicSharedMemorySize, 152992);

    k_prep<<<18, 256, 0, stream>>>(fc_w, fc_b, dec_k, dec_b, Gp, gy, gb);
    k_main<<<64, 1024, 152992, stream>>>(inputs, enc_k, enc_r, enc_b, ae_w1, ae_b1, ae_w2,
                                         dec_r, ad_w1, ad_b1, ad_w2, ff_w, ff_b,
                                         Gp, gy, gb, ws_xenc, (float*)d_out);
}

// Round 13
// 843.059 us; speedup vs baseline: 1.2993x; 1.1467x over previous
//
#include <hip/hip_runtime.h>

#define TT 96
#define FF 32
#define HH 128
#define G4 512
#define LOG2E 1.4426950408889634f

typedef _Float16 h2 __attribute__((ext_vector_type(2)));

__device__ __forceinline__ float fexp2(float x){ return __builtin_amdgcn_exp2f(x); }
__device__ __forceinline__ float frcp(float x){ return __builtin_amdgcn_rcpf(x); }
__device__ __forceinline__ float fsigmoid(float x){ return frcp(1.0f + fexp2(-LOG2E*x)); }
__device__ __forceinline__ float ftanh(float x){
    float u = fexp2(2.0f*LOG2E*x);
    return 1.0f - 2.0f*frcp(1.0f + u);
}
__device__ __forceinline__ h2 pk(float a, float b){
    h2 r; r.x = (_Float16)a; r.y = (_Float16)b; return r;
}
__device__ __forceinline__ unsigned pku(float a, float b){
    return __builtin_bit_cast(unsigned, pk(a, b));
}
__device__ __forceinline__ h2 u2h(unsigned v){ return __builtin_bit_cast(h2, v); }
__device__ __forceinline__ float fdot2(h2 a, h2 b, float c){
#if __has_builtin(__builtin_amdgcn_fdot2)
    return __builtin_amdgcn_fdot2(a, b, c, false);
#else
    return c + (float)a.x*(float)b.x + (float)a.y*(float)b.y;
#endif
}

// ---------------------------------------------------------------------------
// k_prep: G = fc_w[0:128]@dec_k packed f16 pairs, [g][u] uint4 layout.
// gy = fc_w[128]@dec_k; gb = fc_b@dec_k + dec_b.
// ---------------------------------------------------------------------------
__global__ __launch_bounds__(256) void k_prep(const float* __restrict__ fc_w,
                                              const float* __restrict__ fc_b,
                                              const float* __restrict__ dec_k,
                                              const float* __restrict__ dec_b,
                                              h2* __restrict__ Gp,
                                              float* __restrict__ gy,
                                              float* __restrict__ gb){
    int blk = blockIdx.x, tid = threadIdx.x;
    int u0 = tid, u1 = tid + 256;
    if (blk < 16){
        float a0[8], a1[8];
        #pragma unroll
        for (int r = 0; r < 8; ++r){ a0[r] = 0.f; a1[r] = 0.f; }
        for (int m = 0; m < 128; ++m){
            float d0 = dec_k[m*G4 + u0], d1 = dec_k[m*G4 + u1];
            #pragma unroll
            for (int r = 0; r < 8; ++r){
                float w = fc_w[(blk*8 + r)*HH + m];
                a0[r] += w * d0; a1[r] += w * d1;
            }
        }
        #pragma unroll
        for (int c = 0; c < 4; ++c){
            Gp[(blk*G4 + u0)*4 + c] = pk(a0[2*c], a0[2*c+1]);
            Gp[(blk*G4 + u1)*4 + c] = pk(a1[2*c], a1[2*c+1]);
        }
    } else if (blk == 16){
        float a0 = 0.f, a1 = 0.f;
        for (int m = 0; m < 128; ++m){
            float w = fc_w[128*HH + m];
            a0 += w * dec_k[m*G4 + u0]; a1 += w * dec_k[m*G4 + u1];
        }
        gy[u0] = a0; gy[u1] = a1;
    } else {
        float a0 = 0.f, a1 = 0.f;
        for (int m = 0; m < 128; ++m){
            float w = fc_b[m];
            a0 += w * dec_k[m*G4 + u0]; a1 += w * dec_k[m*G4 + u1];
        }
        gb[u0] = a0 + dec_b[u0]; gb[u1] = a1 + dec_b[u1];
    }
}

// ---------------------------------------------------------------------------
// k_enc: round-10 base; round-13: PH-A partial+reduce merged -> tid<128
// computes full PE[j] (32 b128 weight reads + 32 broadcasts). 5 barriers/step.
// ---------------------------------------------------------------------------
__global__ __launch_bounds__(1024, 1) void k_enc(const float* __restrict__ inputs,
                                                 const float* __restrict__ enc_k,
                                                 const float* __restrict__ enc_r,
                                                 const float* __restrict__ enc_b,
                                                 const float* __restrict__ ae_w1,
                                                 const float* __restrict__ ae_b1,
                                                 const float* __restrict__ ae_w2,
                                                 float* __restrict__ ws_xenc){
    extern __shared__ float lds[];
    uint4* KLH4 = (uint4*)lds;            // [4][512] uint4 = 8192 floats
    float* XPJT = lds + 8192;             // [128][33] = 4224
    float* XIN  = lds + 12416;            // [96][32]  = 3072
    float* HST  = lds + 15488;            // 256 (h, s fp32 state)
    float* PP   = lds + 15744;            // 1024 partials
    float* PPZ  = lds + 16768;            // 1024 z-halves
    float* PE   = lds + 17792;            // 128
    float* W2E  = lds + 17920;            // 128
    float* AB1E = lds + 18048;            // 128
    h2*    HSP  = (h2*)(lds + 18176);     // 128 h2
    h2*    XTP  = (h2*)(lds + 18240);     // 16 h2
    uint4* WAE4 = (uint4*)(lds + 18256);  // [32][128] uint4 = 16384 floats
    // total 34640 floats = 138560 B

    const int b = blockIdx.x, tid = threadIdx.x;
    const int u = tid & 511, hf = tid >> 9;
    const float* xin_g = inputs + b*TT*FF;

    for (int i = tid; i < TT*FF; i += 1024) XIN[i] = xin_g[i];
    for (int i = tid; i < 2048; i += 1024){
        int f8 = i >> 9, uu = i & 511;
        uint4 q;
        q.x = pku(enc_k[(f8*8+0)*G4+uu], enc_k[(f8*8+1)*G4+uu]);
        q.y = pku(enc_k[(f8*8+2)*G4+uu], enc_k[(f8*8+3)*G4+uu]);
        q.z = pku(enc_k[(f8*8+4)*G4+uu], enc_k[(f8*8+5)*G4+uu]);
        q.w = pku(enc_k[(f8*8+6)*G4+uu], enc_k[(f8*8+7)*G4+uu]);
        KLH4[i] = q;
    }
    for (int i = tid; i < 4096; i += 1024){
        int j = i & 127, i4g = i >> 7;
        int kbase = (i4g >> 2)*32 + (i4g & 3)*8;
        uint4 wv;
        wv.x = pku(ae_w1[(kbase+0)*HH + j], ae_w1[(kbase+1)*HH + j]);
        wv.y = pku(ae_w1[(kbase+2)*HH + j], ae_w1[(kbase+3)*HH + j]);
        wv.z = pku(ae_w1[(kbase+4)*HH + j], ae_w1[(kbase+5)*HH + j]);
        wv.w = pku(ae_w1[(kbase+6)*HH + j], ae_w1[(kbase+7)*HH + j]);
        WAE4[i] = wv;
    }
    if (tid < 128){ W2E[tid] = ae_w2[tid]; AB1E[tid] = ae_b1[tid]; HSP[tid] = pk(0.f, 0.f); }
    if (tid < 256) HST[tid] = 0.f;

    h2 rp_e[32];
    #pragma unroll
    for (int i = 0; i < 32; ++i)
        rp_e[i] = pk(enc_r[(hf*64 + 2*i)*G4 + u], enc_r[(hf*64 + 2*i+1)*G4 + u]);
    const float eb = (hf == 0) ? enc_b[u] : 0.f;
    __syncthreads();

    {   // XPJT[j][f] = sum_t x[t][f]*ae_w1[(256+t)*128+j]
        int j = tid & 127, fh = tid >> 7;
        float a0=0.f, a1=0.f, a2=0.f, a3=0.f;
        for (int t = 0; t < TT; ++t){
            float w = ae_w1[(256 + t)*HH + j];
            const float* xr = &XIN[t*FF + fh*4];
            a0 += xr[0]*w; a1 += xr[1]*w; a2 += xr[2]*w; a3 += xr[3]*w;
        }
        XPJT[j*33 + fh*4 + 0] = a0;
        XPJT[j*33 + fh*4 + 1] = a1;
        XPJT[j*33 + fh*4 + 2] = a2;
        XPJT[j*33 + fh*4 + 3] = a3;
    }
    __syncthreads();

    const uint4* HSP4 = (const uint4*)HSP;
    const uint4* XTP4 = (const uint4*)XTP;

    for (int t = 0; t < TT; ++t){
        // P1: z-partial h@enc_r (all threads) + FULL PE[j] (tid<128)
        float z = eb;
        {
            float z2 = 0.f;
            #pragma unroll
            for (int i4 = 0; i4 < 8; ++i4){
                uint4 q = HSP4[hf*8 + i4];
                z  = fdot2(u2h(q.x), rp_e[i4*4+0], z);
                z2 = fdot2(u2h(q.y), rp_e[i4*4+1], z2);
                z  = fdot2(u2h(q.z), rp_e[i4*4+2], z);
                z2 = fdot2(u2h(q.w), rp_e[i4*4+3], z2);
            }
            z += z2;
        }
        if (tid < 128){
            float s0 = 0.f, s1 = 0.f;
            #pragma unroll
            for (int m = 0; m < 32; m += 2){
                uint4 hq0 = HSP4[m],     wv0 = WAE4[m*128 + tid];
                uint4 hq1 = HSP4[m + 1], wv1 = WAE4[(m + 1)*128 + tid];
                s0 = fdot2(u2h(hq0.x), u2h(wv0.x), s0);
                s1 = fdot2(u2h(hq0.y), u2h(wv0.y), s1);
                s0 = fdot2(u2h(hq0.z), u2h(wv0.z), s0);
                s1 = fdot2(u2h(hq0.w), u2h(wv0.w), s1);
                s0 = fdot2(u2h(hq1.x), u2h(wv1.x), s0);
                s1 = fdot2(u2h(hq1.y), u2h(wv1.y), s1);
                s0 = fdot2(u2h(hq1.z), u2h(wv1.z), s0);
                s1 = fdot2(u2h(hq1.w), u2h(wv1.w), s1);
            }
            PE[tid] = s0 + s1 + AB1E[tid];
        }
        __syncthreads();  // B1
        // P2: e[f] partials
        {
            int f = tid & 31, jg = tid >> 5;
            float acc = 0.f;
            #pragma unroll
            for (int i = 0; i < 4; ++i){
                int j = jg*4 + i;
                acc += ftanh(PE[j] + XPJT[j*33 + f]) * W2E[j];
            }
            PP[tid] = acc;
        }
        __syncthreads();  // B2
        // P3: softmax (no max-sub) + x_tilde pack on first 32 lanes
        if (tid < 32){
            float e = 0.f;
            #pragma unroll
            for (int g = 0; g < 32; ++g) e += PP[g*32 + tid];
            float p = fexp2(e * LOG2E);
            float ss = p;
            #pragma unroll
            for (int d = 16; d; d >>= 1) ss += __shfl_xor(ss, d, 32);
            float xt = p * frcp(ss) * XIN[t*FF + tid];
            float xt2 = __shfl_xor(xt, 1);
            if (!(tid & 1)) XTP[tid >> 1] = pk(xt, xt2);
        }
        __syncthreads();  // B3
        // P4: z-half += x_tilde@enc_k -> PPZ
        {
            float z2 = 0.f;
            #pragma unroll
            for (int c = 0; c < 2; ++c){
                int f8 = hf*2 + c;
                uint4 kq = KLH4[f8*512 + u];
                uint4 xq = XTP4[f8];
                z  = fdot2(u2h(kq.x), u2h(xq.x), z);
                z2 = fdot2(u2h(kq.y), u2h(xq.y), z2);
                z  = fdot2(u2h(kq.z), u2h(xq.z), z);
                z2 = fdot2(u2h(kq.w), u2h(xq.w), z2);
            }
            PPZ[hf*512 + u] = z + z2;
        }
        __syncthreads();  // B4
        // P5: gates + state
        if (tid < 128){
            int j = tid;
            float zi = PPZ[j]       + PPZ[512 + j];
            float zf = PPZ[128 + j] + PPZ[640 + j];
            float zg = PPZ[256 + j] + PPZ[768 + j];
            float zo = PPZ[384 + j] + PPZ[896 + j];
            float iv = fsigmoid(zi);
            float fv = fsigmoid(zf);
            float gv = ftanh(zg);
            float ov = fsigmoid(zo);
            float cn = fv * HST[128 + j] + iv * gv;
            float hn = ov * ftanh(cn);
            HST[128 + j] = cn;
            HST[j] = hn;
            ws_xenc[(b*TT + t)*HH + j] = hn;
            float hn2 = __shfl_xor(hn, 1);
            float cn2 = __shfl_xor(cn, 1);
            if (!(j & 1)){
                HSP[j >> 1]        = pk(hn, hn2);
                HSP[64 + (j >> 1)] = pk(cn, cn2);
            }
        }
        __syncthreads();  // B5
    }
}

// ---------------------------------------------------------------------------
// k_xept: xeptT[b][j][t] = sum_k x_enc[b][t][k] * ad_w1[(256+k)*128 + j]
// ---------------------------------------------------------------------------
__global__ __launch_bounds__(256) void k_xept(const float* __restrict__ ws_xenc,
                                              const float* __restrict__ ad_w1,
                                              float* __restrict__ ws_xept){
    int b = blockIdx.x, q = blockIdx.y, tid = threadIdx.x;
    int j = tid & 127, th = tid >> 7;
    const float* xb = ws_xenc + b*TT*HH;
    float acc[12];
    #pragma unroll
    for (int i = 0; i < 12; ++i) acc[i] = 0.f;
    for (int k = 0; k < 128; ++k){
        float w = ad_w1[(256 + k)*HH + j];
        #pragma unroll
        for (int i = 0; i < 12; ++i){
            int tp = q*24 + th*12 + i;
            acc[i] += xb[tp*HH + k] * w;
        }
    }
    #pragma unroll
    for (int i = 0; i < 12; ++i){
        int tp = q*24 + th*12 + i;
        ws_xept[(b*HH + j)*TT + tp] = acc[i];
    }
}

// ---------------------------------------------------------------------------
// k_dec: round-10 base; round-13: two partial+reduce pairs merged ->
// tid<128 computes full APJ[j] and full ctx[k]. 6 barriers/step (was 8).
// ---------------------------------------------------------------------------
__global__ __launch_bounds__(1024, 1) void k_dec(const float* __restrict__ inputs,
                                                 const float* __restrict__ dec_r,
                                                 const float* __restrict__ ad_w1,
                                                 const float* __restrict__ ad_b1,
                                                 const float* __restrict__ ad_w2,
                                                 const float* __restrict__ ff_w,
                                                 const float* __restrict__ ff_b,
                                                 const h2* __restrict__ Gp,
                                                 const float* __restrict__ gy,
                                                 const float* __restrict__ gb,
                                                 const float* __restrict__ ws_xenc,
                                                 const float* __restrict__ ws_xept,
                                                 float* __restrict__ out){
    extern __shared__ float lds[];
    uint4* XE4 = (uint4*)lds;             // [12][128] uint4 = 6144 floats
    float* XPT = lds + 6144;              // [128][96] = 12288
    float* PP  = lds + 18432;             // 1024
    float* PPZ = lds + 19456;             // 1024
    float* DST = lds + 20480;             // 256: d, c
    float* APJ = lds + 20736;             // 128
    float* CTX = lds + 20864;             // 128
    float* W2L = lds + 20992;             // 128
    float* SCAL= lds + 21120;             // 8
    h2*    DCP = (h2*)(lds + 21128);      // 64 floats (128 h2)
    h2*    CXP = (h2*)(lds + 21192);      // 32 floats (64 h2)
    h2*    BEP = (h2*)(lds + 21224);      // 32 floats (64 h2, 48 used)
    float* YV  = lds + 21256;             // 96
    uint4* WDC4= (uint4*)(lds + 21352);   // [32][128] uint4 = 16384 floats
    // total 37736 floats = 150944 B

    const int b = blockIdx.x, tid = threadIdx.x;
    const int u = tid & 511, hf = tid >> 9;        // unit, k-half

    {   // x_enc -> LDS f16 t-pairs
        const float* xe_g = ws_xenc + b*TT*HH;
        for (int i = tid; i < 12*HH; i += 1024){
            int t8 = i >> 7, k = i & 127;
            uint4 qq;
            qq.x = pku(xe_g[(t8*8 + 0)*HH + k], xe_g[(t8*8 + 1)*HH + k]);
            qq.y = pku(xe_g[(t8*8 + 2)*HH + k], xe_g[(t8*8 + 3)*HH + k]);
            qq.z = pku(xe_g[(t8*8 + 4)*HH + k], xe_g[(t8*8 + 5)*HH + k]);
            qq.w = pku(xe_g[(t8*8 + 6)*HH + k], xe_g[(t8*8 + 7)*HH + k]);
            XE4[i] = qq;
        }
    }
    {   // xept -> LDS fp32 (one-time, coalesced)
        const float* xp_g = ws_xept + b*HH*TT;
        for (int i = tid; i < HH*TT; i += 1024) XPT[i] = xp_g[i];
    }
    // ad_w1 rows 0..255 -> f16 LDS
    for (int i = tid; i < 4096; i += 1024){
        int j = i & 127, i4g = i >> 7;
        int kbase = (i4g >> 2)*32 + (i4g & 3)*8;
        uint4 wv;
        wv.x = pku(ad_w1[(kbase+0)*HH + j], ad_w1[(kbase+1)*HH + j]);
        wv.y = pku(ad_w1[(kbase+2)*HH + j], ad_w1[(kbase+3)*HH + j]);
        wv.z = pku(ad_w1[(kbase+4)*HH + j], ad_w1[(kbase+5)*HH + j]);
        wv.w = pku(ad_w1[(kbase+6)*HH + j], ad_w1[(kbase+7)*HH + j]);
        WDC4[i] = wv;
    }
    if (tid < TT) YV[tid] = inputs[b*TT*FF + tid*FF + (FF-1)];
    if (tid < 128){ W2L[tid] = ad_w2[tid]; DCP[tid] = pk(0.f, 0.f); }
    if (tid < 256) DST[tid] = 0.f;

    h2 rp[32];
    #pragma unroll
    for (int i = 0; i < 32; ++i)
        rp[i] = pk(dec_r[(hf*64 + 2*i)*G4 + u], dec_r[(hf*64 + 2*i+1)*G4 + u]);
    const float gbr = gb[u], gyr = gy[u];
    const float ab1 = (tid < 128) ? ad_b1[tid] : 0.f;

    __syncthreads();

    const uint4* GQ   = (const uint4*)Gp;
    const uint4* DCP4 = (const uint4*)DCP;
    const uint4* CXP4 = (const uint4*)CXP;
    const uint4* BEP4 = (const uint4*)BEP;

    for (int t = 0; t < TT; ++t){
        // P1: z-partial d@dec_r (all threads) + FULL APJ[j] (tid<128)
        float z = (hf == 0) ? (gbr + YV[t]*gyr) : 0.f;
        {
            float z2 = 0.f;
            #pragma unroll
            for (int i4 = 0; i4 < 8; ++i4){
                uint4 q = DCP4[hf*8 + i4];
                z  = fdot2(u2h(q.x), rp[i4*4+0], z);
                z2 = fdot2(u2h(q.y), rp[i4*4+1], z2);
                z  = fdot2(u2h(q.z), rp[i4*4+2], z);
                z2 = fdot2(u2h(q.w), rp[i4*4+3], z2);
            }
            z += z2;
        }
        if (tid < 128){
            float s0 = 0.f, s1 = 0.f;
            #pragma unroll
            for (int m = 0; m < 32; m += 2){
                uint4 dq0 = DCP4[m],     wv0 = WDC4[m*128 + tid];
                uint4 dq1 = DCP4[m + 1], wv1 = WDC4[(m + 1)*128 + tid];
                s0 = fdot2(u2h(dq0.x), u2h(wv0.x), s0);
                s1 = fdot2(u2h(dq0.y), u2h(wv0.y), s1);
                s0 = fdot2(u2h(dq0.z), u2h(wv0.z), s0);
                s1 = fdot2(u2h(dq0.w), u2h(wv0.w), s1);
                s0 = fdot2(u2h(dq1.x), u2h(wv1.x), s0);
                s1 = fdot2(u2h(dq1.y), u2h(wv1.y), s1);
                s0 = fdot2(u2h(dq1.z), u2h(wv1.z), s0);
                s1 = fdot2(u2h(dq1.w), u2h(wv1.w), s1);
            }
            APJ[tid] = s0 + s1 + ab1;
        }
        __syncthreads();  // B1
        // P2: e[t'] partials (8 j-chunks of 16) — xept from LDS
        {
            int tp = tid & 127, jg = tid >> 7;
            float acc = 0.f;
            if (tp < TT){
                const float* xrow = &XPT[(jg*16)*TT + tp];
                #pragma unroll
                for (int q4 = 0; q4 < 4; ++q4){
                    float4 aj = *(const float4*)&APJ[jg*16 + q4*4];
                    float4 wj = *(const float4*)&W2L[jg*16 + q4*4];
                    acc += ftanh(aj.x + xrow[(q4*4+0)*TT]) * wj.x;
                    acc += ftanh(aj.y + xrow[(q4*4+1)*TT]) * wj.y;
                    acc += ftanh(aj.z + xrow[(q4*4+2)*TT]) * wj.z;
                    acc += ftanh(aj.w + xrow[(q4*4+3)*TT]) * wj.w;
                }
            }
            PP[tid] = acc;
        }
        __syncthreads();  // B2
        // P3: softmax over 96 on wave 0 (no max-sub); packed beta pairs
        if (tid < 64){
            float ea = 0.f;
            #pragma unroll
            for (int g = 0; g < 8; ++g) ea += PP[tid + 128*g];
            float pa = fexp2(ea * LOG2E);
            float pb = 0.f;
            if (tid < 32){
                float ebv = 0.f;
                #pragma unroll
                for (int g = 0; g < 8; ++g) ebv += PP[64 + tid + 128*g];
                pb = fexp2(ebv * LOG2E);
            }
            float ss = pa + pb;
            #pragma unroll
            for (int d = 32; d; d >>= 1) ss += __shfl_xor(ss, d, 64);
            float pa2 = __shfl_xor(pa, 1);
            float pb2 = __shfl_xor(pb, 1);
            if (!(tid & 1)){
                BEP[tid >> 1] = pk(pa, pa2);
                if (tid < 32) BEP[32 + (tid >> 1)] = pk(pb, pb2);
            }
            if (tid == 0) SCAL[0] = frcp(ss);
        }
        __syncthreads();  // B3
        // P4: FULL ctx[k] (tid<128): 12 b128 x_enc reads + beta broadcasts
        if (tid < 128){
            float s0 = 0.f, s1 = 0.f;
            #pragma unroll
            for (int t8 = 0; t8 < 12; t8 += 2){
                uint4 xq0 = XE4[t8*HH + tid],     bb0 = BEP4[t8];
                uint4 xq1 = XE4[(t8+1)*HH + tid], bb1 = BEP4[t8+1];
                s0 = fdot2(u2h(xq0.x), u2h(bb0.x), s0);
                s1 = fdot2(u2h(xq0.y), u2h(bb0.y), s1);
                s0 = fdot2(u2h(xq0.z), u2h(bb0.z), s0);
                s1 = fdot2(u2h(xq0.w), u2h(bb0.w), s1);
                s0 = fdot2(u2h(xq1.x), u2h(bb1.x), s0);
                s1 = fdot2(u2h(xq1.y), u2h(bb1.y), s1);
                s0 = fdot2(u2h(xq1.z), u2h(bb1.z), s0);
                s1 = fdot2(u2h(xq1.w), u2h(bb1.w), s1);
            }
            float cv = (s0 + s1) * SCAL[0];
            CTX[tid] = cv;
            float cv2 = __shfl_xor(cv, 1);
            if (!(tid & 1)) CXP[tid >> 1] = pk(cv, cv2);
        }
        __syncthreads();  // B4
        // P5: z-half += ctx@G (G streamed from L2, groups hf*8..+7)
        {
            float z2 = 0.f;
            #pragma unroll
            for (int gi = 0; gi < 8; ++gi){
                int g = hf*8 + gi;
                uint4 q  = GQ[g*G4 + u];
                uint4 cc = CXP4[g];
                z  = fdot2(u2h(q.x), u2h(cc.x), z);
                z2 = fdot2(u2h(q.y), u2h(cc.y), z2);
                z  = fdot2(u2h(q.z), u2h(cc.z), z);
                z2 = fdot2(u2h(q.w), u2h(cc.w), z2);
            }
            PPZ[hf*512 + u] = z + z2;
        }
        __syncthreads();  // B5
        // P6: gates (combine z-halves) + packed-state update
        if (tid < 128){
            int j = tid;
            float zi = PPZ[j]       + PPZ[512 + j];
            float zf = PPZ[128 + j] + PPZ[640 + j];
            float zg = PPZ[256 + j] + PPZ[768 + j];
            float zo = PPZ[384 + j] + PPZ[896 + j];
            float iv = fsigmoid(zi);
            float fv = fsigmoid(zf);
            float gv = ftanh(zg);
            float ov = fsigmoid(zo);
            float cn = fv * DST[128 + j] + iv * gv;
            float hn = ov * ftanh(cn);
            DST[128 + j] = cn;
            DST[j] = hn;
            float hn2 = __shfl_xor(hn, 1);
            float cn2 = __shfl_xor(cn, 1);
            if (!(j & 1)){
                DCP[j >> 1]        = pk(hn, hn2);
                DCP[64 + (j >> 1)] = pk(cn, cn2);
            }
        }
        __syncthreads();  // B6
    }

    // output: y_pred = [d_n, ctx] @ ff_w + ff_b (fp32)
    {
        int jp = tid & 31, sg = tid >> 5;
        float a = 0.f;
        #pragma unroll
        for (int kk = 0; kk < 8; ++kk){
            int k = sg*8 + kk;
            float val = (k < 128) ? DST[k] : CTX[k - 128];
            a += val * ff_w[k*FF + jp];
        }
        PP[sg*32 + jp] = a;
    }
    __syncthreads();
    if (tid < 32){
        float o = ff_b[tid];
        #pragma unroll
        for (int s = 0; s < 32; ++s) o += PP[s*32 + tid];
        out[b*FF + tid] = o;
    }
}

// ---------------------------------------------------------------------------
extern "C" void kernel_launch(void* const* d_in, const int* in_sizes, int n_in,
                              void* d_out, int out_size, void* d_ws, size_t ws_size,
                              hipStream_t stream) {
    const float* inputs = (const float*)d_in[0];
    const float* enc_k  = (const float*)d_in[1];
    const float* enc_r  = (const float*)d_in[2];
    const float* enc_b  = (const float*)d_in[3];
    const float* ae_w1  = (const float*)d_in[4];
    const float* ae_b1  = (const float*)d_in[5];
    const float* ae_w2  = (const float*)d_in[6];
    // d_in[7] = ae_b2 (softmax-invariant, unused)
    const float* dec_k  = (const float*)d_in[8];
    const float* dec_r  = (const float*)d_in[9];
    const float* dec_b  = (const float*)d_in[10];
    const float* ad_w1  = (const float*)d_in[11];
    const float* ad_b1  = (const float*)d_in[12];
    const float* ad_w2  = (const float*)d_in[13];
    // d_in[14] = ad_b2 (softmax-invariant, unused)
    const float* fc_w   = (const float*)d_in[15];
    const float* fc_b   = (const float*)d_in[16];
    const float* ff_w   = (const float*)d_in[17];
    const float* ff_b   = (const float*)d_in[18];

    float* ws      = (float*)d_ws;
    float* ws_xenc = ws;                     // 64*96*128 floats
    float* ws_xept = ws + 786432;            // 64*128*96 floats
    h2*    Gp      = (h2*)(ws + 1572864);    // 32768 h2 (128 KB)
    float* gy      = ws + 1605632;           // 512
    float* gb      = ws + 1606144;           // 512

    hipFuncSetAttribute((const void*)k_enc, hipFuncAttributeMaxDynamicSharedMemorySize, 138560);
    hipFuncSetAttribute((const void*)k_dec, hipFuncAttributeMaxDynamicSharedMemorySize, 150944);

    k_prep<<<18, 256, 0, stream>>>(fc_w, fc_b, dec_k, dec_b, Gp, gy, gb);
    k_enc<<<64, 1024, 138560, stream>>>(inputs, enc_k, enc_r, enc_b, ae_w1, ae_b1, ae_w2, ws_xenc);
    k_xept<<<dim3(64, 4), 256, 0, stream>>>(ws_xenc, ad_w1, ws_xept);
    k_dec<<<64, 1024, 150944, stream>>>(inputs, dec_r, ad_w1, ad_b1, ad_w2, ff_w, ff_b,
                                        Gp, gy, gb, ws_xenc, ws_xept, (float*)d_out);
}

// Round 14
// 825.063 us; speedup vs baseline: 1.3276x; 1.0218x over previous
//
#include <hip/hip_runtime.h>

#define TT 96
#define FF 32
#define HH 128
#define G4 512
#define LOG2E 1.4426950408889634f

typedef _Float16 h2 __attribute__((ext_vector_type(2)));

__device__ __forceinline__ float fexp2(float x){ return __builtin_amdgcn_exp2f(x); }
__device__ __forceinline__ float frcp(float x){ return __builtin_amdgcn_rcpf(x); }
__device__ __forceinline__ float fsigmoid(float x){ return frcp(1.0f + fexp2(-LOG2E*x)); }
__device__ __forceinline__ float ftanh(float x){
    float u = fexp2(2.0f*LOG2E*x);
    return 1.0f - 2.0f*frcp(1.0f + u);
}
__device__ __forceinline__ h2 pk(float a, float b){
    h2 r; r.x = (_Float16)a; r.y = (_Float16)b; return r;
}
__device__ __forceinline__ unsigned pku(float a, float b){
    return __builtin_bit_cast(unsigned, pk(a, b));
}
__device__ __forceinline__ h2 u2h(unsigned v){ return __builtin_bit_cast(h2, v); }
__device__ __forceinline__ float fdot2(h2 a, h2 b, float c){
#if __has_builtin(__builtin_amdgcn_fdot2)
    return __builtin_amdgcn_fdot2(a, b, c, false);
#else
    return c + (float)a.x*(float)b.x + (float)a.y*(float)b.y;
#endif
}

// ---------------------------------------------------------------------------
// k_prep: G = fc_w[0:128]@dec_k packed f16 pairs, [g][u] uint4 layout.
// gy = fc_w[128]@dec_k; gb = fc_b@dec_k + dec_b.
// ---------------------------------------------------------------------------
__global__ __launch_bounds__(256) void k_prep(const float* __restrict__ fc_w,
                                              const float* __restrict__ fc_b,
                                              const float* __restrict__ dec_k,
                                              const float* __restrict__ dec_b,
                                              h2* __restrict__ Gp,
                                              float* __restrict__ gy,
                                              float* __restrict__ gb){
    int blk = blockIdx.x, tid = threadIdx.x;
    int u0 = tid, u1 = tid + 256;
    if (blk < 16){
        float a0[8], a1[8];
        #pragma unroll
        for (int r = 0; r < 8; ++r){ a0[r] = 0.f; a1[r] = 0.f; }
        for (int m = 0; m < 128; ++m){
            float d0 = dec_k[m*G4 + u0], d1 = dec_k[m*G4 + u1];
            #pragma unroll
            for (int r = 0; r < 8; ++r){
                float w = fc_w[(blk*8 + r)*HH + m];
                a0[r] += w * d0; a1[r] += w * d1;
            }
        }
        #pragma unroll
        for (int c = 0; c < 4; ++c){
            Gp[(blk*G4 + u0)*4 + c] = pk(a0[2*c], a0[2*c+1]);
            Gp[(blk*G4 + u1)*4 + c] = pk(a1[2*c], a1[2*c+1]);
        }
    } else if (blk == 16){
        float a0 = 0.f, a1 = 0.f;
        for (int m = 0; m < 128; ++m){
            float w = fc_w[128*HH + m];
            a0 += w * dec_k[m*G4 + u0]; a1 += w * dec_k[m*G4 + u1];
        }
        gy[u0] = a0; gy[u1] = a1;
    } else {
        float a0 = 0.f, a1 = 0.f;
        for (int m = 0; m < 128; ++m){
            float w = fc_b[m];
            a0 += w * dec_k[m*G4 + u0]; a1 += w * dec_k[m*G4 + u1];
        }
        gb[u0] = a0 + dec_b[u0]; gb[u1] = a1 + dec_b[u1];
    }
}

// ---------------------------------------------------------------------------
// k_enc: round-10 loop verbatim. Round-14: gates phase also stores hn as f16
// into XEF; after the time loop the same block computes xept (was a separate
// kernel) from LDS-resident x_enc and writes ws_xept.
// ---------------------------------------------------------------------------
__global__ __launch_bounds__(1024, 1) void k_enc(const float* __restrict__ inputs,
                                                 const float* __restrict__ enc_k,
                                                 const float* __restrict__ enc_r,
                                                 const float* __restrict__ enc_b,
                                                 const float* __restrict__ ae_w1,
                                                 const float* __restrict__ ae_b1,
                                                 const float* __restrict__ ae_w2,
                                                 const float* __restrict__ ad_w1,
                                                 float* __restrict__ ws_xenc,
                                                 float* __restrict__ ws_xept){
    extern __shared__ float lds[];
    uint4* KLH4 = (uint4*)lds;            // [4][512] uint4 = 8192 floats
    float* XPJT = lds + 8192;             // [128][33] = 4224
    float* XIN  = lds + 12416;            // [96][32]  = 3072
    float* HST  = lds + 15488;            // 256 (h, s fp32 state)
    float* PP   = lds + 15744;            // 1024 partials
    float* PPZ  = lds + 16768;            // 1024 z-halves
    float* PE   = lds + 17792;            // 128
    float* W2E  = lds + 17920;            // 128
    float* AB1E = lds + 18048;            // 128
    h2*    HSP  = (h2*)(lds + 18176);     // 128 h2
    h2*    XTP  = (h2*)(lds + 18240);     // 16 h2
    uint4* WAE4 = (uint4*)(lds + 18256);  // [32][128] uint4 = 16384 floats
    _Float16* XEF = (_Float16*)(lds + 34640); // [96][128] f16 = 24576 B
    // total 163136 B (cap 163840)

    const int b = blockIdx.x, tid = threadIdx.x;
    const int u = tid & 511, hf = tid >> 9;
    const int j7 = tid & 127, g8 = tid >> 7;
    const float* xin_g = inputs + b*TT*FF;

    for (int i = tid; i < TT*FF; i += 1024) XIN[i] = xin_g[i];
    for (int i = tid; i < 2048; i += 1024){
        int f8 = i >> 9, uu = i & 511;
        uint4 q;
        q.x = pku(enc_k[(f8*8+0)*G4+uu], enc_k[(f8*8+1)*G4+uu]);
        q.y = pku(enc_k[(f8*8+2)*G4+uu], enc_k[(f8*8+3)*G4+uu]);
        q.z = pku(enc_k[(f8*8+4)*G4+uu], enc_k[(f8*8+5)*G4+uu]);
        q.w = pku(enc_k[(f8*8+6)*G4+uu], enc_k[(f8*8+7)*G4+uu]);
        KLH4[i] = q;
    }
    for (int i = tid; i < 4096; i += 1024){
        int j = i & 127, i4g = i >> 7;
        int kbase = (i4g >> 2)*32 + (i4g & 3)*8;
        uint4 wv;
        wv.x = pku(ae_w1[(kbase+0)*HH + j], ae_w1[(kbase+1)*HH + j]);
        wv.y = pku(ae_w1[(kbase+2)*HH + j], ae_w1[(kbase+3)*HH + j]);
        wv.z = pku(ae_w1[(kbase+4)*HH + j], ae_w1[(kbase+5)*HH + j]);
        wv.w = pku(ae_w1[(kbase+6)*HH + j], ae_w1[(kbase+7)*HH + j]);
        WAE4[i] = wv;
    }
    if (tid < 128){ W2E[tid] = ae_w2[tid]; AB1E[tid] = ae_b1[tid]; HSP[tid] = pk(0.f, 0.f); }
    if (tid < 256) HST[tid] = 0.f;

    h2 rp_e[32];
    #pragma unroll
    for (int i = 0; i < 32; ++i)
        rp_e[i] = pk(enc_r[(hf*64 + 2*i)*G4 + u], enc_r[(hf*64 + 2*i+1)*G4 + u]);
    const float eb = (hf == 0) ? enc_b[u] : 0.f;
    __syncthreads();

    {   // XPJT[j][f] = sum_t x[t][f]*ae_w1[(256+t)*128+j]
        int j = tid & 127, fh = tid >> 7;
        float a0=0.f, a1=0.f, a2=0.f, a3=0.f;
        for (int t = 0; t < TT; ++t){
            float w = ae_w1[(256 + t)*HH + j];
            const float* xr = &XIN[t*FF + fh*4];
            a0 += xr[0]*w; a1 += xr[1]*w; a2 += xr[2]*w; a3 += xr[3]*w;
        }
        XPJT[j*33 + fh*4 + 0] = a0;
        XPJT[j*33 + fh*4 + 1] = a1;
        XPJT[j*33 + fh*4 + 2] = a2;
        XPJT[j*33 + fh*4 + 3] = a3;
    }
    __syncthreads();

    const uint4* HSP4 = (const uint4*)HSP;
    const uint4* XTP4 = (const uint4*)XTP;

    for (int t = 0; t < TT; ++t){
        // PH-A: att-proj partials, weights from LDS (b128)
        {
            float a0 = 0.f, a1 = 0.f;
            #pragma unroll
            for (int i4 = 0; i4 < 4; ++i4){
                uint4 q  = HSP4[g8*4 + i4];
                uint4 wv = WAE4[(g8*4 + i4)*128 + j7];
                a0 = fdot2(u2h(q.x), u2h(wv.x), a0);
                a1 = fdot2(u2h(q.y), u2h(wv.y), a1);
                a0 = fdot2(u2h(q.z), u2h(wv.z), a0);
                a1 = fdot2(u2h(q.w), u2h(wv.w), a1);
            }
            PP[tid] = a0 + a1;
        }
        float z = eb;
        {
            float z2 = 0.f;
            #pragma unroll
            for (int i4 = 0; i4 < 8; ++i4){
                uint4 q = HSP4[hf*8 + i4];
                z  = fdot2(u2h(q.x), rp_e[i4*4+0], z);
                z2 = fdot2(u2h(q.y), rp_e[i4*4+1], z2);
                z  = fdot2(u2h(q.z), rp_e[i4*4+2], z);
                z2 = fdot2(u2h(q.w), rp_e[i4*4+3], z2);
            }
            z += z2;
        }
        __syncthreads();
        if (tid < 128){
            float s = AB1E[tid];
            #pragma unroll
            for (int g = 0; g < 8; ++g) s += PP[tid + 128*g];
            PE[tid] = s;
        }
        __syncthreads();
        {
            int f = tid & 31, jg = tid >> 5;
            float acc = 0.f;
            #pragma unroll
            for (int i = 0; i < 4; ++i){
                int j = jg*4 + i;
                acc += ftanh(PE[j] + XPJT[j*33 + f]) * W2E[j];
            }
            PP[tid] = acc;
        }
        __syncthreads();
        if (tid < 32){
            float e = 0.f;
            #pragma unroll
            for (int g = 0; g < 32; ++g) e += PP[g*32 + tid];
            float p = fexp2(e * LOG2E);
            float ss = p;
            #pragma unroll
            for (int d = 16; d; d >>= 1) ss += __shfl_xor(ss, d, 32);
            float xt = p * frcp(ss) * XIN[t*FF + tid];
            float xt2 = __shfl_xor(xt, 1);
            if (!(tid & 1)) XTP[tid >> 1] = pk(xt, xt2);
        }
        __syncthreads();
        {
            float z2 = 0.f;
            #pragma unroll
            for (int c = 0; c < 2; ++c){
                int f8 = hf*2 + c;
                uint4 kq = KLH4[f8*512 + u];
                uint4 xq = XTP4[f8];
                z  = fdot2(u2h(kq.x), u2h(xq.x), z);
                z2 = fdot2(u2h(kq.y), u2h(xq.y), z2);
                z  = fdot2(u2h(kq.z), u2h(xq.z), z);
                z2 = fdot2(u2h(kq.w), u2h(xq.w), z2);
            }
            PPZ[hf*512 + u] = z + z2;
        }
        __syncthreads();
        if (tid < 128){
            int j = tid;
            float zi = PPZ[j]       + PPZ[512 + j];
            float zf = PPZ[128 + j] + PPZ[640 + j];
            float zg = PPZ[256 + j] + PPZ[768 + j];
            float zo = PPZ[384 + j] + PPZ[896 + j];
            float iv = fsigmoid(zi);
            float fv = fsigmoid(zf);
            float gv = ftanh(zg);
            float ov = fsigmoid(zo);
            float cn = fv * HST[128 + j] + iv * gv;
            float hn = ov * ftanh(cn);
            HST[128 + j] = cn;
            HST[j] = hn;
            ws_xenc[(b*TT + t)*HH + j] = hn;
            XEF[t*HH + j] = (_Float16)hn;      // f16 copy for xept tail
            float hn2 = __shfl_xor(hn, 1);
            float cn2 = __shfl_xor(cn, 1);
            if (!(j & 1)){
                HSP[j >> 1]        = pk(hn, hn2);
                HSP[64 + (j >> 1)] = pk(cn, cn2);
            }
        }
        __syncthreads();
    }

    // xept tail (was k_xept): ws_xept[(b*HH+j)*TT+tp] = sum_k xe[tp][k]*ad_w1[(256+k)*HH+j]
    {
        int j = tid & 127, th = tid >> 7;     // th: 8 groups x 12 t'
        float acc[12];
        #pragma unroll
        for (int i = 0; i < 12; ++i) acc[i] = 0.f;
        for (int k = 0; k < 128; ++k){
            float w = ad_w1[(256 + k)*HH + j];
            #pragma unroll
            for (int i = 0; i < 12; ++i)
                acc[i] += (float)XEF[(th*12 + i)*HH + k] * w;   // wave-uniform -> broadcast
        }
        #pragma unroll
        for (int i = 0; i < 12; ++i)
            ws_xept[(b*HH + j)*TT + th*12 + i] = acc[i];
    }
}

// ---------------------------------------------------------------------------
// k_dec: round-13 verbatim (477 µs): merged full-APJ and full-ctx phases,
// 6 barriers/step, weights in LDS, rp[32] only reg array.
// ---------------------------------------------------------------------------
__global__ __launch_bounds__(1024, 1) void k_dec(const float* __restrict__ inputs,
                                                 const float* __restrict__ dec_r,
                                                 const float* __restrict__ ad_w1,
                                                 const float* __restrict__ ad_b1,
                                                 const float* __restrict__ ad_w2,
                                                 const float* __restrict__ ff_w,
                                                 const float* __restrict__ ff_b,
                                                 const h2* __restrict__ Gp,
                                                 const float* __restrict__ gy,
                                                 const float* __restrict__ gb,
                                                 const float* __restrict__ ws_xenc,
                                                 const float* __restrict__ ws_xept,
                                                 float* __restrict__ out){
    extern __shared__ float lds[];
    uint4* XE4 = (uint4*)lds;             // [12][128] uint4 = 6144 floats
    float* XPT = lds + 6144;              // [128][96] = 12288
    float* PP  = lds + 18432;             // 1024
    float* PPZ = lds + 19456;             // 1024
    float* DST = lds + 20480;             // 256: d, c
    float* APJ = lds + 20736;             // 128
    float* CTX = lds + 20864;             // 128
    float* W2L = lds + 20992;             // 128
    float* SCAL= lds + 21120;             // 8
    h2*    DCP = (h2*)(lds + 21128);      // 64 floats (128 h2)
    h2*    CXP = (h2*)(lds + 21192);      // 32 floats (64 h2)
    h2*    BEP = (h2*)(lds + 21224);      // 32 floats (64 h2, 48 used)
    float* YV  = lds + 21256;             // 96
    uint4* WDC4= (uint4*)(lds + 21352);   // [32][128] uint4 = 16384 floats
    // total 37736 floats = 150944 B

    const int b = blockIdx.x, tid = threadIdx.x;
    const int u = tid & 511, hf = tid >> 9;        // unit, k-half

    {   // x_enc -> LDS f16 t-pairs
        const float* xe_g = ws_xenc + b*TT*HH;
        for (int i = tid; i < 12*HH; i += 1024){
            int t8 = i >> 7, k = i & 127;
            uint4 qq;
            qq.x = pku(xe_g[(t8*8 + 0)*HH + k], xe_g[(t8*8 + 1)*HH + k]);
            qq.y = pku(xe_g[(t8*8 + 2)*HH + k], xe_g[(t8*8 + 3)*HH + k]);
            qq.z = pku(xe_g[(t8*8 + 4)*HH + k], xe_g[(t8*8 + 5)*HH + k]);
            qq.w = pku(xe_g[(t8*8 + 6)*HH + k], xe_g[(t8*8 + 7)*HH + k]);
            XE4[i] = qq;
        }
    }
    {   // xept -> LDS fp32 (one-time, coalesced)
        const float* xp_g = ws_xept + b*HH*TT;
        for (int i = tid; i < HH*TT; i += 1024) XPT[i] = xp_g[i];
    }
    // ad_w1 rows 0..255 -> f16 LDS
    for (int i = tid; i < 4096; i += 1024){
        int j = i & 127, i4g = i >> 7;
        int kbase = (i4g >> 2)*32 + (i4g & 3)*8;
        uint4 wv;
        wv.x = pku(ad_w1[(kbase+0)*HH + j], ad_w1[(kbase+1)*HH + j]);
        wv.y = pku(ad_w1[(kbase+2)*HH + j], ad_w1[(kbase+3)*HH + j]);
        wv.z = pku(ad_w1[(kbase+4)*HH + j], ad_w1[(kbase+5)*HH + j]);
        wv.w = pku(ad_w1[(kbase+6)*HH + j], ad_w1[(kbase+7)*HH + j]);
        WDC4[i] = wv;
    }
    if (tid < TT) YV[tid] = inputs[b*TT*FF + tid*FF + (FF-1)];
    if (tid < 128){ W2L[tid] = ad_w2[tid]; DCP[tid] = pk(0.f, 0.f); }
    if (tid < 256) DST[tid] = 0.f;

    h2 rp[32];
    #pragma unroll
    for (int i = 0; i < 32; ++i)
        rp[i] = pk(dec_r[(hf*64 + 2*i)*G4 + u], dec_r[(hf*64 + 2*i+1)*G4 + u]);
    const float gbr = gb[u], gyr = gy[u];
    const float ab1 = (tid < 128) ? ad_b1[tid] : 0.f;

    __syncthreads();

    const uint4* GQ   = (const uint4*)Gp;
    const uint4* DCP4 = (const uint4*)DCP;
    const uint4* CXP4 = (const uint4*)CXP;
    const uint4* BEP4 = (const uint4*)BEP;

    for (int t = 0; t < TT; ++t){
        // P1: z-partial d@dec_r (all threads) + FULL APJ[j] (tid<128)
        float z = (hf == 0) ? (gbr + YV[t]*gyr) : 0.f;
        {
            float z2 = 0.f;
            #pragma unroll
            for (int i4 = 0; i4 < 8; ++i4){
                uint4 q = DCP4[hf*8 + i4];
                z  = fdot2(u2h(q.x), rp[i4*4+0], z);
                z2 = fdot2(u2h(q.y), rp[i4*4+1], z2);
                z  = fdot2(u2h(q.z), rp[i4*4+2], z);
                z2 = fdot2(u2h(q.w), rp[i4*4+3], z2);
            }
            z += z2;
        }
        if (tid < 128){
            float s0 = 0.f, s1 = 0.f;
            #pragma unroll
            for (int m = 0; m < 32; m += 2){
                uint4 dq0 = DCP4[m],     wv0 = WDC4[m*128 + tid];
                uint4 dq1 = DCP4[m + 1], wv1 = WDC4[(m + 1)*128 + tid];
                s0 = fdot2(u2h(dq0.x), u2h(wv0.x), s0);
                s1 = fdot2(u2h(dq0.y), u2h(wv0.y), s1);
                s0 = fdot2(u2h(dq0.z), u2h(wv0.z), s0);
                s1 = fdot2(u2h(dq0.w), u2h(wv0.w), s1);
                s0 = fdot2(u2h(dq1.x), u2h(wv1.x), s0);
                s1 = fdot2(u2h(dq1.y), u2h(wv1.y), s1);
                s0 = fdot2(u2h(dq1.z), u2h(wv1.z), s0);
                s1 = fdot2(u2h(dq1.w), u2h(wv1.w), s1);
            }
            APJ[tid] = s0 + s1 + ab1;
        }
        __syncthreads();  // B1
        // P2: e[t'] partials (8 j-chunks of 16) — xept from LDS
        {
            int tp = tid & 127, jg = tid >> 7;
            float acc = 0.f;
            if (tp < TT){
                const float* xrow = &XPT[(jg*16)*TT + tp];
                #pragma unroll
                for (int q4 = 0; q4 < 4; ++q4){
                    float4 aj = *(const float4*)&APJ[jg*16 + q4*4];
                    float4 wj = *(const float4*)&W2L[jg*16 + q4*4];
                    acc += ftanh(aj.x + xrow[(q4*4+0)*TT]) * wj.x;
                    acc += ftanh(aj.y + xrow[(q4*4+1)*TT]) * wj.y;
                    acc += ftanh(aj.z + xrow[(q4*4+2)*TT]) * wj.z;
                    acc += ftanh(aj.w + xrow[(q4*4+3)*TT]) * wj.w;
                }
            }
            PP[tid] = acc;
        }
        __syncthreads();  // B2
        // P3: softmax over 96 on wave 0 (no max-sub); packed beta pairs
        if (tid < 64){
            float ea = 0.f;
            #pragma unroll
            for (int g = 0; g < 8; ++g) ea += PP[tid + 128*g];
            float pa = fexp2(ea * LOG2E);
            float pb = 0.f;
            if (tid < 32){
                float ebv = 0.f;
                #pragma unroll
                for (int g = 0; g < 8; ++g) ebv += PP[64 + tid + 128*g];
                pb = fexp2(ebv * LOG2E);
            }
            float ss = pa + pb;
            #pragma unroll
            for (int d = 32; d; d >>= 1) ss += __shfl_xor(ss, d, 64);
            float pa2 = __shfl_xor(pa, 1);
            float pb2 = __shfl_xor(pb, 1);
            if (!(tid & 1)){
                BEP[tid >> 1] = pk(pa, pa2);
                if (tid < 32) BEP[32 + (tid >> 1)] = pk(pb, pb2);
            }
            if (tid == 0) SCAL[0] = frcp(ss);
        }
        __syncthreads();  // B3
        // P4: FULL ctx[k] (tid<128)
        if (tid < 128){
            float s0 = 0.f, s1 = 0.f;
            #pragma unroll
            for (int t8 = 0; t8 < 12; t8 += 2){
                uint4 xq0 = XE4[t8*HH + tid],     bb0 = BEP4[t8];
                uint4 xq1 = XE4[(t8+1)*HH + tid], bb1 = BEP4[t8+1];
                s0 = fdot2(u2h(xq0.x), u2h(bb0.x), s0);
                s1 = fdot2(u2h(xq0.y), u2h(bb0.y), s1);
                s0 = fdot2(u2h(xq0.z), u2h(bb0.z), s0);
                s1 = fdot2(u2h(xq0.w), u2h(bb0.w), s1);
                s0 = fdot2(u2h(xq1.x), u2h(bb1.x), s0);
                s1 = fdot2(u2h(xq1.y), u2h(bb1.y), s1);
                s0 = fdot2(u2h(xq1.z), u2h(bb1.z), s0);
                s1 = fdot2(u2h(xq1.w), u2h(bb1.w), s1);
            }
            float cv = (s0 + s1) * SCAL[0];
            CTX[tid] = cv;
            float cv2 = __shfl_xor(cv, 1);
            if (!(tid & 1)) CXP[tid >> 1] = pk(cv, cv2);
        }
        __syncthreads();  // B4
        // P5: z-half += ctx@G (G streamed from L2, groups hf*8..+7)
        {
            float z2 = 0.f;
            #pragma unroll
            for (int gi = 0; gi < 8; ++gi){
                int g = hf*8 + gi;
                uint4 q  = GQ[g*G4 + u];
                uint4 cc = CXP4[g];
                z  = fdot2(u2h(q.x), u2h(cc.x), z);
                z2 = fdot2(u2h(q.y), u2h(cc.y), z2);
                z  = fdot2(u2h(q.z), u2h(cc.z), z);
                z2 = fdot2(u2h(q.w), u2h(cc.w), z2);
            }
            PPZ[hf*512 + u] = z + z2;
        }
        __syncthreads();  // B5
        // P6: gates (combine z-halves) + packed-state update
        if (tid < 128){
            int j = tid;
            float zi = PPZ[j]       + PPZ[512 + j];
            float zf = PPZ[128 + j] + PPZ[640 + j];
            float zg = PPZ[256 + j] + PPZ[768 + j];
            float zo = PPZ[384 + j] + PPZ[896 + j];
            float iv = fsigmoid(zi);
            float fv = fsigmoid(zf);
            float gv = ftanh(zg);
            float ov = fsigmoid(zo);
            float cn = fv * DST[128 + j] + iv * gv;
            float hn = ov * ftanh(cn);
            DST[128 + j] = cn;
            DST[j] = hn;
            float hn2 = __shfl_xor(hn, 1);
            float cn2 = __shfl_xor(cn, 1);
            if (!(j & 1)){
                DCP[j >> 1]        = pk(hn, hn2);
                DCP[64 + (j >> 1)] = pk(cn, cn2);
            }
        }
        __syncthreads();  // B6
    }

    // output: y_pred = [d_n, ctx] @ ff_w + ff_b (fp32)
    {
        int jp = tid & 31, sg = tid >> 5;
        float a = 0.f;
        #pragma unroll
        for (int kk = 0; kk < 8; ++kk){
            int k = sg*8 + kk;
            float val = (k < 128) ? DST[k] : CTX[k - 128];
            a += val * ff_w[k*FF + jp];
        }
        PP[sg*32 + jp] = a;
    }
    __syncthreads();
    if (tid < 32){
        float o = ff_b[tid];
        #pragma unroll
        for (int s = 0; s < 32; ++s) o += PP[s*32 + tid];
        out[b*FF + tid] = o;
    }
}

// ---------------------------------------------------------------------------
extern "C" void kernel_launch(void* const* d_in, const int* in_sizes, int n_in,
                              void* d_out, int out_size, void* d_ws, size_t ws_size,
                              hipStream_t stream) {
    const float* inputs = (const float*)d_in[0];
    const float* enc_k  = (const float*)d_in[1];
    const float* enc_r  = (const float*)d_in[2];
    const float* enc_b  = (const float*)d_in[3];
    const float* ae_w1  = (const float*)d_in[4];
    const float* ae_b1  = (const float*)d_in[5];
    const float* ae_w2  = (const float*)d_in[6];
    // d_in[7] = ae_b2 (softmax-invariant, unused)
    const float* dec_k  = (const float*)d_in[8];
    const float* dec_r  = (const float*)d_in[9];
    const float* dec_b  = (const float*)d_in[10];
    const float* ad_w1  = (const float*)d_in[11];
    const float* ad_b1  = (const float*)d_in[12];
    const float* ad_w2  = (const float*)d_in[13];
    // d_in[14] = ad_b2 (softmax-invariant, unused)
    const float* fc_w   = (const float*)d_in[15];
    const float* fc_b   = (const float*)d_in[16];
    const float* ff_w   = (const float*)d_in[17];
    const float* ff_b   = (const float*)d_in[18];

    float* ws      = (float*)d_ws;
    float* ws_xenc = ws;                     // 64*96*128 floats
    float* ws_xept = ws + 786432;            // 64*128*96 floats
    h2*    Gp      = (h2*)(ws + 1572864);    // 32768 h2 (128 KB)
    float* gy      = ws + 1605632;           // 512
    float* gb      = ws + 1606144;           // 512

    hipFuncSetAttribute((const void*)k_enc, hipFuncAttributeMaxDynamicSharedMemorySize, 163136);
    hipFuncSetAttribute((const void*)k_dec, hipFuncAttributeMaxDynamicSharedMemorySize, 150944);

    k_prep<<<18, 256, 0, stream>>>(fc_w, fc_b, dec_k, dec_b, Gp, gy, gb);
    k_enc<<<64, 1024, 163136, stream>>>(inputs, enc_k, enc_r, enc_b, ae_w1, ae_b1, ae_w2,
                                        ad_w1, ws_xenc, ws_xept);
    k_dec<<<64, 1024, 150944, stream>>>(inputs, dec_r, ad_w1, ad_b1, ad_w2, ff_w, ff_b,
                                        Gp, gy, gb, ws_xenc, ws_xept, (float*)d_out);
}